// Round 1
// baseline (19772.258 us; speedup 1.0000x reference)
//
#include <hip/hip_runtime.h>

// ST-GCN classifier forward, fp32 baseline.
// Design: A-first GCN ((A X) W), biases before InstanceNorm dropped (cancel),
// stats via dedicated reduction kernels, conv fused with norm1+relu on LDS
// load, epilogue fuses norm2+relu+residual+relu. Batch-chunked to fit ws.

#define NN 62
#define KK 9

// ---------------- prep: gcn-normalized adjacency + adj passthrough ----------
__global__ __launch_bounds__(256) void k_prep(const float* __restrict__ adj,
                                              float* __restrict__ a_norm,
                                              float* __restrict__ out_adj) {
  __shared__ float dinv[NN];
  int tid = threadIdx.x;
  if (tid < NN) {
    float s = 1.0f;  // self loop
    for (int n = 0; n < NN; n++) s += adj[tid * NN + n];
    dinv[tid] = (s > 0.f) ? rsqrtf(fmaxf(s, 1e-5f)) : 0.f;
  }
  __syncthreads();
  for (int idx = tid; idx < NN * NN; idx += 256) {
    int m = idx / NN, n = idx - m * NN;
    float ah = adj[idx] + ((m == n) ? 1.f : 0.f);
    a_norm[idx] = dinv[m] * ah * dinv[n];
    out_adj[idx] = adj[idx];
  }
}

// ------------- weight transposes: conv [o][ci][k]->[ci][k][o]; res [o][ci]->[ci][o]
__global__ __launch_bounds__(256) void k_wt(const float* __restrict__ wc, float* __restrict__ wt, int C,
                                            const float* __restrict__ wr, float* __restrict__ wrt, int CIN) {
  int stride = gridDim.x * blockDim.x;
  int total = C * C * KK;
  for (int i = blockIdx.x * blockDim.x + threadIdx.x; i < total; i += stride) {
    int o = i / (C * KK);
    int r = i - o * C * KK;
    int ci = r / KK;
    int k = r - ci * KK;
    wt[(ci * KK + k) * C + o] = wc[i];
  }
  int t2 = C * CIN;
  for (int i = blockIdx.x * blockDim.x + threadIdx.x; i < t2; i += stride) {
    int o = i / CIN, ci = i - o * CIN;
    wrt[ci * C + o] = wr[i];
  }
}

// ---------------- spatial mix: xs[b,f,m,t] = sum_n a[m,n] * in[b,f,n,t] -----
// LAYX: input is x in (b,n,t,f) layout (block 0); else (b,f,n,t) chunk-local.
template <int CIN, int TIN, bool LAYX>
__global__ __launch_bounds__(256) void k_spatial(const float* __restrict__ in,
                                                 const float* __restrict__ a_norm,
                                                 float* __restrict__ xs, int b0) {
  constexpr int TT = 128;
  constexpr int RS = TT + 4;
  __shared__ float tile[NN * RS];
  __shared__ float aL[NN * NN];
  int t0 = blockIdx.x * TT;
  int f = blockIdx.y;
  int bl = blockIdx.z;
  int tid = threadIdx.x;
  for (int i = tid; i < NN * NN; i += 256) aL[i] = a_norm[i];
  for (int i = tid; i < NN * TT; i += 256) {
    int n = i / TT, tl = i - n * TT;
    float v;
    if (LAYX)
      v = in[(((size_t)(b0 + bl) * NN + n) * TIN + (t0 + tl)) * CIN + f];
    else
      v = in[(((size_t)bl * CIN + f) * NN + n) * TIN + t0 + tl];
    tile[n * RS + tl] = v;
  }
  __syncthreads();
  constexpr int T4 = TT / 4;
  for (int task = tid; task < NN * T4; task += 256) {
    int m = task / T4;
    int t4 = (task - m * T4) * 4;
    float4 acc = {0.f, 0.f, 0.f, 0.f};
    for (int n = 0; n < NN; n++) {
      float av = aL[m * NN + n];
      float4 xv = *reinterpret_cast<const float4*>(&tile[n * RS + t4]);
      acc.x += av * xv.x;
      acc.y += av * xv.y;
      acc.z += av * xv.z;
      acc.w += av * xv.w;
    }
    *reinterpret_cast<float4*>(&xs[(((size_t)bl * CIN + f) * NN + m) * TIN + t0 + t4]) = acc;
  }
}

// ---------------- channel mix: y[b,o,s] = sum_f wg[f,o] * xs[b,f,s] ---------
template <int CIN, int COUT, int TIN>
__global__ __launch_bounds__(256) void k_wmix(const float* __restrict__ xs,
                                              const float* __restrict__ wg,
                                              float* __restrict__ y) {
  constexpr int S = NN * TIN;
  constexpr int O4L = (COUT / 4 < 16) ? COUT / 4 : 16;  // o4-lanes
  constexpr int SL = 256 / O4L;                          // s4-lanes
  constexpr int ST = SL * 4;                             // s-tile
  constexpr int RS = ST + 4;
  __shared__ float xt[CIN * RS];
  __shared__ float wL[CIN * COUT];
  int s0 = blockIdx.x * ST;
  int bl = blockIdx.y;
  int tid = threadIdx.x;
  for (int i = tid; i < CIN * COUT; i += 256) wL[i] = wg[i];
  for (int i = tid; i < CIN * ST; i += 256) {
    int f = i / ST, sl = i - f * ST;
    xt[f * RS + sl] = xs[((size_t)bl * CIN + f) * S + s0 + sl];
  }
  __syncthreads();
  int s4 = (tid % SL) * 4;
  int o4l = tid / SL;
  constexpr int PASSES = COUT / (4 * O4L);
  for (int op = 0; op < PASSES; op++) {
    int o0 = op * (4 * O4L) + o4l * 4;
    float4 a0 = {0, 0, 0, 0}, a1 = {0, 0, 0, 0}, a2 = {0, 0, 0, 0}, a3 = {0, 0, 0, 0};
    for (int f = 0; f < CIN; f++) {
      float4 xv = *reinterpret_cast<const float4*>(&xt[f * RS + s4]);
      float4 wv = *reinterpret_cast<const float4*>(&wL[f * COUT + o0]);
      a0.x += wv.x * xv.x; a0.y += wv.x * xv.y; a0.z += wv.x * xv.z; a0.w += wv.x * xv.w;
      a1.x += wv.y * xv.x; a1.y += wv.y * xv.y; a1.z += wv.y * xv.z; a1.w += wv.y * xv.w;
      a2.x += wv.z * xv.x; a2.y += wv.z * xv.y; a2.z += wv.z * xv.z; a2.w += wv.z * xv.w;
      a3.x += wv.w * xv.x; a3.y += wv.w * xv.y; a3.z += wv.w * xv.z; a3.w += wv.w * xv.w;
    }
    *reinterpret_cast<float4*>(&y[((size_t)bl * COUT + o0 + 0) * S + s0 + s4]) = a0;
    *reinterpret_cast<float4*>(&y[((size_t)bl * COUT + o0 + 1) * S + s0 + s4]) = a1;
    *reinterpret_cast<float4*>(&y[((size_t)bl * COUT + o0 + 2) * S + s0 + s4]) = a2;
    *reinterpret_cast<float4*>(&y[((size_t)bl * COUT + o0 + 3) * S + s0 + s4]) = a3;
  }
}

// ---------------- per-(b,c) mean / rsigma over S elems ----------------------
__global__ __launch_bounds__(256) void k_stats(const float* __restrict__ src,
                                               float* __restrict__ stats, int S) {
  int c = blockIdx.x, bl = blockIdx.y;
  int C = gridDim.x;
  const float* p = src + ((size_t)bl * C + c) * S;
  float s = 0.f, s2 = 0.f;
  for (int i = threadIdx.x; i < S; i += 256) {
    float v = p[i];
    s += v;
    s2 += v * v;
  }
  for (int off = 32; off; off >>= 1) {
    s += __shfl_down(s, off);
    s2 += __shfl_down(s2, off);
  }
  __shared__ float ls[4], ls2[4];
  int w = threadIdx.x >> 6;
  if ((threadIdx.x & 63) == 0) {
    ls[w] = s;
    ls2[w] = s2;
  }
  __syncthreads();
  if (threadIdx.x == 0) {
    float S1 = ls[0] + ls[1] + ls[2] + ls[3];
    float S2 = ls2[0] + ls2[1] + ls2[2] + ls2[3];
    float m = S1 / (float)S;
    float v = S2 / (float)S - m * m;
    stats[((size_t)bl * C + c) * 2 + 0] = m;
    stats[((size_t)bl * C + c) * 2 + 1] = rsqrtf(fmaxf(v, 0.f) + 1e-5f);
  }
}

// ---------------- temporal conv, input normalized+relu on the fly ------------
// wt layout [ci][k][o]; out c[b,o,n,t'] WITHOUT bias (cancels in next IN).
template <int C, int TIN, int STRIDE>
__global__ __launch_bounds__(256) void k_conv(const float* __restrict__ y,
                                              const float* __restrict__ wt,
                                              const float* __restrict__ stats,
                                              float* __restrict__ cbuf) {
  constexpr int TOUT = TIN / STRIDE;
  constexpr int TT = 64;
  constexpr int SPAN = STRIDE * TT + 8;
  constexpr int OL = C / 8;    // o-lanes
  constexpr int TL = 256 / OL; // t-lanes
  constexpr int TP = TT / TL;  // outputs per thread in t
  constexpr int YL = STRIDE * (TP - 1) + KK;
  __shared__ float yt[C * SPAN];
  __shared__ float stL[2 * C];
  int tb = blockIdx.x;
  int n = blockIdx.y;
  int bl = blockIdx.z;
  int t0 = tb * TT;
  int tin0 = STRIDE * t0 - 4;
  int tid = threadIdx.x;
  for (int i = tid; i < 2 * C; i += 256) stL[i] = stats[(size_t)bl * 2 * C + i];
  __syncthreads();
  for (int i = tid; i < C * SPAN; i += 256) {
    int ci = i / SPAN, p = i - ci * SPAN;
    int t = tin0 + p;
    float v = 0.f;
    if (t >= 0 && t < TIN) {
      float m = stL[2 * ci], rs = stL[2 * ci + 1];
      v = fmaxf((y[(((size_t)bl * C + ci) * NN + n) * TIN + t] - m) * rs, 0.f);
    }
    yt[i] = v;
  }
  __syncthreads();
  int ol = tid / TL, tl = tid - ol * TL;
  int o0 = ol * 8;
  int tp0 = tl * TP;
  float acc[8][TP];
#pragma unroll
  for (int oo = 0; oo < 8; oo++)
#pragma unroll
    for (int tt = 0; tt < TP; tt++) acc[oo][tt] = 0.f;
  for (int ci = 0; ci < C; ci++) {
    float yv[YL];
    const float* row = &yt[ci * SPAN + STRIDE * tp0];
#pragma unroll
    for (int j = 0; j < YL; j++) yv[j] = row[j];
    const float* wrow = &wt[(ci * KK) * C + o0];
#pragma unroll
    for (int k = 0; k < KK; k++) {
      float4 w0 = *reinterpret_cast<const float4*>(&wrow[k * C]);
      float4 w1 = *reinterpret_cast<const float4*>(&wrow[k * C + 4]);
      float wreg[8] = {w0.x, w0.y, w0.z, w0.w, w1.x, w1.y, w1.z, w1.w};
#pragma unroll
      for (int oo = 0; oo < 8; oo++)
#pragma unroll
        for (int tt = 0; tt < TP; tt++) acc[oo][tt] += wreg[oo] * yv[STRIDE * tt + k];
    }
  }
#pragma unroll
  for (int oo = 0; oo < 8; oo++) {
    size_t base = (((size_t)bl * C + o0 + oo) * NN + n) * TOUT + t0 + tp0;
#pragma unroll
    for (int tt = 0; tt < TP; tt++) cbuf[base + tt] = acc[oo][tt];
  }
}

// ------- epilogue: out = relu( relu((c-m2)*rs2) + res(in) + br ) ------------
template <int CIN, int COUT, int TOUT, int STRIDE, bool LAYX>
__global__ __launch_bounds__(256) void k_post(const float* __restrict__ cbuf,
                                              const float* __restrict__ stats,
                                              const float* __restrict__ in,
                                              const float* __restrict__ wrt,
                                              const float* __restrict__ br,
                                              float* __restrict__ out, int b0) {
  constexpr int TT = 64;
  constexpr int TIN_ = TOUT * STRIDE;
  __shared__ float inT[CIN * TT];
  __shared__ float wL[CIN * COUT];
  __shared__ float brL[COUT];
  __shared__ float stL[2 * COUT];
  int t0 = blockIdx.x * TT, n = blockIdx.y, bl = blockIdx.z;
  int tid = threadIdx.x;
  for (int i = tid; i < CIN * COUT; i += 256) wL[i] = wrt[i];
  if (tid < COUT) brL[tid] = br[tid];
  for (int i = tid; i < 2 * COUT; i += 256) stL[i] = stats[(size_t)bl * 2 * COUT + i];
  for (int i = tid; i < CIN * TT; i += 256) {
    int ci = i / TT, tl = i - ci * TT;
    int t = STRIDE * (t0 + tl);
    float v;
    if (LAYX)
      v = in[(((size_t)(b0 + bl) * NN + n) * TIN_ + t) * CIN + ci];
    else
      v = in[(((size_t)bl * CIN + ci) * NN + n) * TIN_ + t];
    inT[i] = v;
  }
  __syncthreads();
  int tl = tid & 63;
  int o4 = tid >> 6;
  int t = t0 + tl;
  for (int op = 0; op < COUT / 16; op++) {
    int o0 = op * 16 + o4 * 4;
    float accA[4] = {0.f, 0.f, 0.f, 0.f};
    for (int ci = 0; ci < CIN; ci++) {
      float xv = inT[ci * TT + tl];
      float4 wv = *reinterpret_cast<const float4*>(&wL[ci * COUT + o0]);
      accA[0] += wv.x * xv;
      accA[1] += wv.y * xv;
      accA[2] += wv.z * xv;
      accA[3] += wv.w * xv;
    }
#pragma unroll
    for (int q = 0; q < 4; q++) {
      int o = o0 + q;
      float m = stL[2 * o], rs = stL[2 * o + 1];
      float cv = cbuf[(((size_t)bl * COUT + o) * NN + n) * TOUT + t];
      float v = fmaxf((cv - m) * rs, 0.f) + accA[q] + brL[o];
      out[(((size_t)bl * COUT + o) * NN + n) * TOUT + t] = fmaxf(v, 0.f);
    }
  }
}

// ---------------- node-mean pool: pooled[b,t,c] = mean_n src[b,c,n,t] -------
__global__ __launch_bounds__(256) void k_pool(const float* __restrict__ src,
                                              float* __restrict__ pooled) {
  constexpr int CP = 128, TPZ = 512, TT = 128;
  int t0 = blockIdx.x * TT;
  int bl = blockIdx.y;
  int tlane = threadIdx.x % TT;
  int chalf = threadIdx.x / TT;
  int t = t0 + tlane;
  for (int c = chalf * 64; c < chalf * 64 + 64; c++) {
    float s = 0.f;
    for (int n = 0; n < NN; n++) s += src[(((size_t)bl * CP + c) * NN + n) * TPZ + t];
    pooled[((size_t)bl * TPZ + t) * CP + c] = s * (1.f / NN);
  }
}

// ---------------- attention scores -> softmax weights -----------------------
__global__ __launch_bounds__(256) void k_attn(const float* __restrict__ pooled,
                                              const float* __restrict__ w1,
                                              const float* __restrict__ b1,
                                              const float* __restrict__ w2,
                                              const float* __restrict__ b2v,
                                              float* __restrict__ wgt) {
  __shared__ float w1L[128 * 64];
  __shared__ float w2L[64];
  __shared__ float b1L[64];
  __shared__ float sc[512];
  __shared__ float red[4];
  int bl = blockIdx.x;
  int tid = threadIdx.x;
  for (int i = tid; i < 128 * 64; i += 256) w1L[i] = w1[i];
  if (tid < 64) {
    w2L[tid] = w2[tid];
    b1L[tid] = b1[tid];
  }
  __syncthreads();
  for (int t = tid; t < 512; t += 256) {
    float hid[64];
#pragma unroll
    for (int j = 0; j < 64; j++) hid[j] = b1L[j];
    const float* pv = &pooled[((size_t)bl * 512 + t) * 128];
    for (int c = 0; c < 128; c++) {
      float x = pv[c];
#pragma unroll
      for (int j = 0; j < 64; j++) hid[j] += x * w1L[c * 64 + j];
    }
    float s = b2v[0];
#pragma unroll
    for (int j = 0; j < 64; j++) s += tanhf(hid[j]) * w2L[j];
    sc[t] = s;
  }
  __syncthreads();
  float mx = -1e30f;
  for (int t = tid; t < 512; t += 256) mx = fmaxf(mx, sc[t]);
  for (int off = 32; off; off >>= 1) mx = fmaxf(mx, __shfl_down(mx, off));
  if ((tid & 63) == 0) red[tid >> 6] = mx;
  __syncthreads();
  mx = fmaxf(fmaxf(red[0], red[1]), fmaxf(red[2], red[3]));
  __syncthreads();
  float sum = 0.f;
  for (int t = tid; t < 512; t += 256) {
    float e = expf(sc[t] - mx);
    sc[t] = e;
    sum += e;
  }
  for (int off = 32; off; off >>= 1) sum += __shfl_down(sum, off);
  if ((tid & 63) == 0) red[tid >> 6] = sum;
  __syncthreads();
  float inv = 1.f / (red[0] + red[1] + red[2] + red[3]);
  for (int t = tid; t < 512; t += 256) wgt[(size_t)bl * 512 + t] = sc[t] * inv;
}

// ---------------- weighted feature + logits ---------------------------------
__global__ __launch_bounds__(128) void k_feat(const float* __restrict__ pooled,
                                              const float* __restrict__ wgt,
                                              const float* __restrict__ fcw,
                                              const float* __restrict__ fcb,
                                              float* __restrict__ out, int b0) {
  __shared__ float featL[128];
  int bl = blockIdx.x;
  int c = threadIdx.x;
  float s = 0.f;
  for (int t = 0; t < 512; t++)
    s += pooled[((size_t)bl * 512 + t) * 128 + c] * wgt[(size_t)bl * 512 + t];
  featL[c] = s;
  __syncthreads();
  if (c < 3) {
    float l = fcb[c];
    for (int cc = 0; cc < 128; cc++) l += featL[cc] * fcw[cc * 3 + c];
    out[(size_t)(b0 + bl) * 3 + c] = l;
  }
}

// ============================================================================
extern "C" void kernel_launch(void* const* d_in, const int* in_sizes, int n_in,
                              void* d_out, int out_size, void* d_ws, size_t ws_size,
                              hipStream_t stream) {
  (void)in_sizes; (void)n_in; (void)out_size;
  const float* x = (const float*)d_in[0];
  const float* adj = (const float*)d_in[1];
  const float* gw0 = (const float*)d_in[2];
  const float* cw0 = (const float*)d_in[4];
  const float* rw0 = (const float*)d_in[6];
  const float* rb0 = (const float*)d_in[7];
  const float* gw1 = (const float*)d_in[8];
  const float* cw1 = (const float*)d_in[10];
  const float* rw1 = (const float*)d_in[12];
  const float* rb1 = (const float*)d_in[13];
  const float* gw2 = (const float*)d_in[14];
  const float* cw2 = (const float*)d_in[16];
  const float* rw2 = (const float*)d_in[18];
  const float* rb2 = (const float*)d_in[19];
  const float* aw1 = (const float*)d_in[20];
  const float* ab1 = (const float*)d_in[21];
  const float* aw2 = (const float*)d_in[22];
  const float* ab2 = (const float*)d_in[23];
  const float* fcw = (const float*)d_in[24];
  const float* fcb = (const float*)d_in[25];
  float* out = (float*)d_out;
  float* ws = (float*)d_ws;

  // shared ws region
  float* a_norm = ws;            // 3844
  float* wt0 = a_norm + 3844;    // 32*32*9   = 9216
  float* wt1 = wt0 + 9216;       // 64*64*9   = 36864
  float* wt2 = wt1 + 36864;      // 128*128*9 = 147456
  float* wrt0 = wt2 + 147456;    // 5*32   = 160
  float* wrt1 = wrt0 + 160;      // 32*64  = 2048
  float* wrt2 = wrt1 + 2048;     // 64*128 = 8192
  float* chunk_base = wrt2 + 8192;
  size_t shared_floats = (size_t)(chunk_base - ws);

  const size_t PS_A = 4063232;   // max of block0/block2 outputs (128*62*512)
  const size_t PS_D = 2031616;   // block1 output (64*62*512)
  const size_t PS_XS = 2031616;  // max xs
  const size_t PS_Y = 4063232;   // max gcn out (64*62*1024)
  const size_t PS_C = 4063232;   // max conv out (128*62*512)
  const size_t per_sample = PS_A + PS_D + PS_XS + PS_Y + PS_C + 65536 + 512 + 256 + 256;

  size_t avail = ws_size / sizeof(float);
  long cap = 1;
  if (avail > shared_floats) cap = (long)((avail - shared_floats) / per_sample);
  int Bc = (int)cap;
  if (Bc < 1) Bc = 1;
  if (Bc > 32) Bc = 32;

  // one-time prep
  k_prep<<<dim3(1), dim3(256), 0, stream>>>(adj, a_norm, out + 96);
  k_wt<<<dim3(64), dim3(256), 0, stream>>>(cw0, wt0, 32, rw0, wrt0, 5);
  k_wt<<<dim3(160), dim3(256), 0, stream>>>(cw1, wt1, 64, rw1, wrt1, 32);
  k_wt<<<dim3(576), dim3(256), 0, stream>>>(cw2, wt2, 128, rw2, wrt2, 64);

  for (int b0 = 0; b0 < 32; b0 += Bc) {
    int bc = (32 - b0 < Bc) ? (32 - b0) : Bc;
    float* stats1 = chunk_base;                         // Bc*256
    float* stats2 = stats1 + (size_t)Bc * 256;          // Bc*256
    float* pooled = stats2 + (size_t)Bc * 256;          // Bc*65536
    float* wgt = pooled + (size_t)Bc * 65536;           // Bc*512
    float* bufA = wgt + (size_t)Bc * 512;
    float* bufD = bufA + (size_t)Bc * PS_A;
    float* bufXS = bufD + (size_t)Bc * PS_D;
    float* bufY = bufXS + (size_t)Bc * PS_XS;
    float* bufC = bufY + (size_t)Bc * PS_Y;

    // ---- block 0: Cin=5 -> Cout=32, T 1024->1024, stride 1, input = x ----
    k_spatial<5, 1024, true><<<dim3(8, 5, bc), dim3(256), 0, stream>>>(x, a_norm, bufXS, b0);
    k_wmix<5, 32, 1024><<<dim3(496, bc), dim3(256), 0, stream>>>(bufXS, gw0, bufY);
    k_stats<<<dim3(32, bc), dim3(256), 0, stream>>>(bufY, stats1, 63488);
    k_conv<32, 1024, 1><<<dim3(16, NN, bc), dim3(256), 0, stream>>>(bufY, wt0, stats1, bufC);
    k_stats<<<dim3(32, bc), dim3(256), 0, stream>>>(bufC, stats2, 63488);
    k_post<5, 32, 1024, 1, true><<<dim3(16, NN, bc), dim3(256), 0, stream>>>(
        bufC, stats2, x, wrt0, rb0, bufA, b0);

    // ---- block 1: 32 -> 64, T 1024->512, stride 2, input = bufA ----
    k_spatial<32, 1024, false><<<dim3(8, 32, bc), dim3(256), 0, stream>>>(bufA, a_norm, bufXS, b0);
    k_wmix<32, 64, 1024><<<dim3(992, bc), dim3(256), 0, stream>>>(bufXS, gw1, bufY);
    k_stats<<<dim3(64, bc), dim3(256), 0, stream>>>(bufY, stats1, 63488);
    k_conv<64, 1024, 2><<<dim3(8, NN, bc), dim3(256), 0, stream>>>(bufY, wt1, stats1, bufC);
    k_stats<<<dim3(64, bc), dim3(256), 0, stream>>>(bufC, stats2, 31744);
    k_post<32, 64, 512, 2, false><<<dim3(8, NN, bc), dim3(256), 0, stream>>>(
        bufC, stats2, bufA, wrt1, rb1, bufD, b0);

    // ---- block 2: 64 -> 128, T 512->512, stride 1, input = bufD ----
    k_spatial<64, 512, false><<<dim3(4, 64, bc), dim3(256), 0, stream>>>(bufD, a_norm, bufXS, b0);
    k_wmix<64, 128, 512><<<dim3(496, bc), dim3(256), 0, stream>>>(bufXS, gw2, bufY);
    k_stats<<<dim3(128, bc), dim3(256), 0, stream>>>(bufY, stats1, 31744);
    k_conv<128, 512, 1><<<dim3(8, NN, bc), dim3(256), 0, stream>>>(bufY, wt2, stats1, bufC);
    k_stats<<<dim3(128, bc), dim3(256), 0, stream>>>(bufC, stats2, 31744);
    k_post<64, 128, 512, 1, false><<<dim3(8, NN, bc), dim3(256), 0, stream>>>(
        bufC, stats2, bufD, wrt2, rb2, bufA, b0);

    // ---- head ----
    k_pool<<<dim3(4, bc), dim3(256), 0, stream>>>(bufA, pooled);
    k_attn<<<dim3(bc), dim3(256), 0, stream>>>(pooled, aw1, ab1, aw2, ab2, wgt);
    k_feat<<<dim3(bc), dim3(128), 0, stream>>>(pooled, wgt, fcw, fcb, out, b0);
  }
}

// Round 2
// 11828.213 us; speedup vs baseline: 1.6716x; 1.6716x over previous
//
#include <hip/hip_runtime.h>

// ST-GCN classifier forward, fp32. Round 2: full-batch head outside the
// chunk loop, 512-block pool, stats as 4 partials finalized in consumers,
// 3-buffer reuse (B1/B2/B3), coalesced block-0 spatial.

#define NN 62
#define KK 9
#define NP 4  // stats partials

// ---------------- prep: gcn-normalized adjacency + adj passthrough ----------
__global__ __launch_bounds__(256) void k_prep(const float* __restrict__ adj,
                                              float* __restrict__ a_norm,
                                              float* __restrict__ out_adj) {
  __shared__ float dinv[NN];
  int tid = threadIdx.x;
  if (tid < NN) {
    float s = 1.0f;  // self loop
    for (int n = 0; n < NN; n++) s += adj[tid * NN + n];
    dinv[tid] = (s > 0.f) ? rsqrtf(fmaxf(s, 1e-5f)) : 0.f;
  }
  __syncthreads();
  for (int idx = tid; idx < NN * NN; idx += 256) {
    int m = idx / NN, n = idx - m * NN;
    float ah = adj[idx] + ((m == n) ? 1.f : 0.f);
    a_norm[idx] = dinv[m] * ah * dinv[n];
    out_adj[idx] = adj[idx];
  }
}

// ------------- weight transposes: conv [o][ci][k]->[ci][k][o]; res [o][ci]->[ci][o]
__global__ __launch_bounds__(256) void k_wt(const float* __restrict__ wc, float* __restrict__ wt, int C,
                                            const float* __restrict__ wr, float* __restrict__ wrt, int CIN) {
  int stride = gridDim.x * blockDim.x;
  int total = C * C * KK;
  for (int i = blockIdx.x * blockDim.x + threadIdx.x; i < total; i += stride) {
    int o = i / (C * KK);
    int r = i - o * C * KK;
    int ci = r / KK;
    int k = r - ci * KK;
    wt[(ci * KK + k) * C + o] = wc[i];
  }
  int t2 = C * CIN;
  for (int i = blockIdx.x * blockDim.x + threadIdx.x; i < t2; i += stride) {
    int o = i / CIN, ci = i - o * CIN;
    wrt[ci * C + o] = wr[i];
  }
}

// ---------------- block-0 spatial: coalesced (t,f) reads of x ---------------
// xs[b,f,m,t] = sum_n a[m,n] * x[b0+b, n, t, f]   (CIN=5, TIN=1024)
template <int TT>
__global__ __launch_bounds__(256) void k_spatial0(const float* __restrict__ x,
                                                  const float* __restrict__ a_norm,
                                                  float* __restrict__ xs, int b0) {
  constexpr int CIN = 5, TIN = 1024;
  constexpr int ROW = TT * CIN;
  __shared__ float xt[NN * ROW];
  __shared__ float aL[NN * NN];
  int t0 = blockIdx.x * TT;
  int mh = blockIdx.y;  // m-half: 62 = 31*2
  int bl = blockIdx.z;
  int tid = threadIdx.x;
  for (int i = tid; i < NN * NN; i += 256) aL[i] = a_norm[i];
  for (int i = tid; i < NN * ROW; i += 256) {
    int n = i / ROW, r = i - n * ROW;
    xt[i] = x[((size_t)((b0 + bl) * NN + n) * TIN + t0) * CIN + r];
  }
  __syncthreads();
  int m0 = mh * 31;
  for (int task = tid; task < CIN * 31 * TT; task += 256) {
    int f = task / (31 * TT);
    int rem = task - f * (31 * TT);
    int mi = rem / TT;
    int tl = rem - mi * TT;
    int m = m0 + mi;
    float acc = 0.f;
    for (int n = 0; n < NN; n++) acc += aL[m * NN + n] * xt[n * ROW + tl * CIN + f];
    xs[(((size_t)bl * CIN + f) * NN + m) * TIN + t0 + tl] = acc;
  }
}

// ---------------- generic spatial mix (chunk-local (b,f,n,t) input) ---------
template <int CIN, int TIN>
__global__ __launch_bounds__(256) void k_spatial(const float* __restrict__ in,
                                                 const float* __restrict__ a_norm,
                                                 float* __restrict__ xs) {
  constexpr int TT = 128;
  constexpr int RS = TT + 4;
  __shared__ float tile[NN * RS];
  __shared__ float aL[NN * NN];
  int t0 = blockIdx.x * TT;
  int f = blockIdx.y;
  int bl = blockIdx.z;
  int tid = threadIdx.x;
  for (int i = tid; i < NN * NN; i += 256) aL[i] = a_norm[i];
  for (int i = tid; i < NN * TT; i += 256) {
    int n = i / TT, tl = i - n * TT;
    tile[n * RS + tl] = in[(((size_t)bl * CIN + f) * NN + n) * TIN + t0 + tl];
  }
  __syncthreads();
  constexpr int T4 = TT / 4;
  for (int task = tid; task < NN * T4; task += 256) {
    int m = task / T4;
    int t4 = (task - m * T4) * 4;
    float4 acc = {0.f, 0.f, 0.f, 0.f};
    for (int n = 0; n < NN; n++) {
      float av = aL[m * NN + n];
      float4 xv = *reinterpret_cast<const float4*>(&tile[n * RS + t4]);
      acc.x += av * xv.x;
      acc.y += av * xv.y;
      acc.z += av * xv.z;
      acc.w += av * xv.w;
    }
    *reinterpret_cast<float4*>(&xs[(((size_t)bl * CIN + f) * NN + m) * TIN + t0 + t4]) = acc;
  }
}

// ---------------- channel mix: y[b,o,s] = sum_f wg[f,o] * xs[b,f,s] ---------
template <int CIN, int COUT, int TIN>
__global__ __launch_bounds__(256) void k_wmix(const float* __restrict__ xs,
                                              const float* __restrict__ wg,
                                              float* __restrict__ y) {
  constexpr int S = NN * TIN;
  constexpr int O4L = (COUT / 4 < 16) ? COUT / 4 : 16;
  constexpr int SL = 256 / O4L;
  constexpr int ST = SL * 4;
  constexpr int RS = ST + 4;
  __shared__ float xt[CIN * RS];
  __shared__ float wL[CIN * COUT];
  int s0 = blockIdx.x * ST;
  int bl = blockIdx.y;
  int tid = threadIdx.x;
  for (int i = tid; i < CIN * COUT; i += 256) wL[i] = wg[i];
  for (int i = tid; i < CIN * ST; i += 256) {
    int f = i / ST, sl = i - f * ST;
    xt[f * RS + sl] = xs[((size_t)bl * CIN + f) * S + s0 + sl];
  }
  __syncthreads();
  int s4 = (tid % SL) * 4;
  int o4l = tid / SL;
  constexpr int PASSES = COUT / (4 * O4L);
  for (int op = 0; op < PASSES; op++) {
    int o0 = op * (4 * O4L) + o4l * 4;
    float4 a0 = {0, 0, 0, 0}, a1 = {0, 0, 0, 0}, a2 = {0, 0, 0, 0}, a3 = {0, 0, 0, 0};
    for (int f = 0; f < CIN; f++) {
      float4 xv = *reinterpret_cast<const float4*>(&xt[f * RS + s4]);
      float4 wv = *reinterpret_cast<const float4*>(&wL[f * COUT + o0]);
      a0.x += wv.x * xv.x; a0.y += wv.x * xv.y; a0.z += wv.x * xv.z; a0.w += wv.x * xv.w;
      a1.x += wv.y * xv.x; a1.y += wv.y * xv.y; a1.z += wv.y * xv.z; a1.w += wv.y * xv.w;
      a2.x += wv.z * xv.x; a2.y += wv.z * xv.y; a2.z += wv.z * xv.z; a2.w += wv.z * xv.w;
      a3.x += wv.w * xv.x; a3.y += wv.w * xv.y; a3.z += wv.w * xv.z; a3.w += wv.w * xv.w;
    }
    *reinterpret_cast<float4*>(&y[((size_t)bl * COUT + o0 + 0) * S + s0 + s4]) = a0;
    *reinterpret_cast<float4*>(&y[((size_t)bl * COUT + o0 + 1) * S + s0 + s4]) = a1;
    *reinterpret_cast<float4*>(&y[((size_t)bl * COUT + o0 + 2) * S + s0 + s4]) = a2;
    *reinterpret_cast<float4*>(&y[((size_t)bl * COUT + o0 + 3) * S + s0 + s4]) = a3;
  }
}

// ---------------- per-(b,c) stats partials: sum, sumsq over S/NP ------------
__global__ __launch_bounds__(256) void k_statsP(const float* __restrict__ src,
                                                float* __restrict__ part, int S) {
  int c = blockIdx.x, p = blockIdx.y, bl = blockIdx.z;
  int C = gridDim.x;
  int chunkS = S / NP;
  int s0 = p * chunkS;
  const float* q = src + ((size_t)bl * C + c) * S;
  float s = 0.f, s2 = 0.f;
  for (int i = s0 + threadIdx.x; i < s0 + chunkS; i += 256) {
    float v = q[i];
    s += v;
    s2 += v * v;
  }
  for (int off = 32; off; off >>= 1) {
    s += __shfl_down(s, off);
    s2 += __shfl_down(s2, off);
  }
  __shared__ float ls[4], ls2[4];
  int w = threadIdx.x >> 6;
  if ((threadIdx.x & 63) == 0) {
    ls[w] = s;
    ls2[w] = s2;
  }
  __syncthreads();
  if (threadIdx.x == 0) {
    size_t o = (((size_t)bl * C + c) * NP + p) * 2;
    part[o + 0] = ls[0] + ls[1] + ls[2] + ls[3];
    part[o + 1] = ls2[0] + ls2[1] + ls2[2] + ls2[3];
  }
}

// finalize partials -> (mean, rsigma) into stL[2*C]; call with all threads, sync after
template <int C, int S>
__device__ __forceinline__ void finalize_stats(const float* __restrict__ part, int bl,
                                               float* __restrict__ stL, int tid) {
  for (int c = tid; c < C; c += 256) {
    float s = 0.f, s2 = 0.f;
#pragma unroll
    for (int p = 0; p < NP; p++) {
      size_t o = (((size_t)bl * C + c) * NP + p) * 2;
      s += part[o];
      s2 += part[o + 1];
    }
    float m = s / (float)S;
    float v = s2 / (float)S - m * m;
    stL[2 * c] = m;
    stL[2 * c + 1] = rsqrtf(fmaxf(v, 0.f) + 1e-5f);
  }
}

// ---------------- temporal conv, input normalized+relu on the fly ------------
template <int C, int TIN, int STRIDE>
__global__ __launch_bounds__(256) void k_conv(const float* __restrict__ y,
                                              const float* __restrict__ wt,
                                              const float* __restrict__ part,
                                              float* __restrict__ cbuf) {
  constexpr int TOUT = TIN / STRIDE;
  constexpr int TT = 64;
  constexpr int SPAN = STRIDE * TT + 8;
  constexpr int OL = C / 8;
  constexpr int TL = 256 / OL;
  constexpr int TP = TT / TL;
  constexpr int YL = STRIDE * (TP - 1) + KK;
  __shared__ float yt[C * SPAN];
  __shared__ float stL[2 * C];
  int tb = blockIdx.x;
  int n = blockIdx.y;
  int bl = blockIdx.z;
  int t0 = tb * TT;
  int tin0 = STRIDE * t0 - 4;
  int tid = threadIdx.x;
  finalize_stats<C, NN * TIN>(part, bl, stL, tid);
  __syncthreads();
  for (int i = tid; i < C * SPAN; i += 256) {
    int ci = i / SPAN, p = i - ci * SPAN;
    int t = tin0 + p;
    float v = 0.f;
    if (t >= 0 && t < TIN) {
      float m = stL[2 * ci], rs = stL[2 * ci + 1];
      v = fmaxf((y[(((size_t)bl * C + ci) * NN + n) * TIN + t] - m) * rs, 0.f);
    }
    yt[i] = v;
  }
  __syncthreads();
  int ol = tid / TL, tl = tid - ol * TL;
  int o0 = ol * 8;
  int tp0 = tl * TP;
  float acc[8][TP];
#pragma unroll
  for (int oo = 0; oo < 8; oo++)
#pragma unroll
    for (int tt = 0; tt < TP; tt++) acc[oo][tt] = 0.f;
  for (int ci = 0; ci < C; ci++) {
    float yv[YL];
    const float* row = &yt[ci * SPAN + STRIDE * tp0];
#pragma unroll
    for (int j = 0; j < YL; j++) yv[j] = row[j];
    const float* wrow = &wt[(ci * KK) * C + o0];
#pragma unroll
    for (int k = 0; k < KK; k++) {
      float4 w0 = *reinterpret_cast<const float4*>(&wrow[k * C]);
      float4 w1 = *reinterpret_cast<const float4*>(&wrow[k * C + 4]);
      float wreg[8] = {w0.x, w0.y, w0.z, w0.w, w1.x, w1.y, w1.z, w1.w};
#pragma unroll
      for (int oo = 0; oo < 8; oo++)
#pragma unroll
        for (int tt = 0; tt < TP; tt++) acc[oo][tt] += wreg[oo] * yv[STRIDE * tt + k];
    }
  }
#pragma unroll
  for (int oo = 0; oo < 8; oo++) {
    size_t base = (((size_t)bl * C + o0 + oo) * NN + n) * TOUT + t0 + tp0;
#pragma unroll
    for (int tt = 0; tt < TP; tt++) cbuf[base + tt] = acc[oo][tt];
  }
}

// ------- epilogue: out = relu( relu((c-m2)*rs2) + res(in) + br ) ------------
template <int CIN, int COUT, int TOUT, int STRIDE, bool LAYX>
__global__ __launch_bounds__(256) void k_post(const float* __restrict__ cbuf,
                                              const float* __restrict__ part,
                                              const float* __restrict__ in,
                                              const float* __restrict__ wrt,
                                              const float* __restrict__ br,
                                              float* __restrict__ out, int b0) {
  constexpr int TT = 64;
  constexpr int TIN_ = TOUT * STRIDE;
  __shared__ float inT[CIN * TT];
  __shared__ float wL[CIN * COUT];
  __shared__ float brL[COUT];
  __shared__ float stL[2 * COUT];
  int t0 = blockIdx.x * TT, n = blockIdx.y, bl = blockIdx.z;
  int tid = threadIdx.x;
  for (int i = tid; i < CIN * COUT; i += 256) wL[i] = wrt[i];
  if (tid < COUT) brL[tid] = br[tid];
  finalize_stats<COUT, NN * TOUT>(part, bl, stL, tid);
  for (int i = tid; i < CIN * TT; i += 256) {
    int ci = i / TT, tl = i - ci * TT;
    int t = STRIDE * (t0 + tl);
    float v;
    if (LAYX)
      v = in[(((size_t)(b0 + bl) * NN + n) * TIN_ + t) * CIN + ci];
    else
      v = in[(((size_t)bl * CIN + ci) * NN + n) * TIN_ + t];
    inT[i] = v;
  }
  __syncthreads();
  int tl = tid & 63;
  int o4 = tid >> 6;
  int t = t0 + tl;
  for (int op = 0; op < COUT / 16; op++) {
    int o0 = op * 16 + o4 * 4;
    float accA[4] = {0.f, 0.f, 0.f, 0.f};
    for (int ci = 0; ci < CIN; ci++) {
      float xv = inT[ci * TT + tl];
      float4 wv = *reinterpret_cast<const float4*>(&wL[ci * COUT + o0]);
      accA[0] += wv.x * xv;
      accA[1] += wv.y * xv;
      accA[2] += wv.z * xv;
      accA[3] += wv.w * xv;
    }
#pragma unroll
    for (int q = 0; q < 4; q++) {
      int o = o0 + q;
      float m = stL[2 * o], rs = stL[2 * o + 1];
      float cv = cbuf[(((size_t)bl * COUT + o) * NN + n) * TOUT + t];
      float v = fmaxf((cv - m) * rs, 0.f) + accA[q] + brL[o];
      out[(((size_t)bl * COUT + o) * NN + n) * TOUT + t] = fmaxf(v, 0.f);
    }
  }
}

// ---------------- node-mean pool: pooled[b0+b,t,c] = mean_n src[b,c,n,t] ----
__global__ __launch_bounds__(256) void k_pool(const float* __restrict__ src,
                                              float* __restrict__ pooled, int b0) {
  constexpr int CP = 128, TPZ = 512;
  int t = blockIdx.x * 64 + (threadIdx.x & 63);
  int c = blockIdx.y * 4 + (threadIdx.x >> 6);
  int bl = blockIdx.z;
  const float* p = src + ((size_t)bl * CP + c) * NN * TPZ + t;
  float s = 0.f;
  for (int n = 0; n < NN; n++) s += p[(size_t)n * TPZ];
  pooled[((size_t)(b0 + bl) * TPZ + t) * CP + c] = s * (1.f / NN);
}

// ---------------- attention scores (full batch) -----------------------------
__global__ __launch_bounds__(128) void k_attn1(const float* __restrict__ pooled,
                                               const float* __restrict__ w1,
                                               const float* __restrict__ b1,
                                               const float* __restrict__ w2,
                                               const float* __restrict__ b2v,
                                               float* __restrict__ score) {
  __shared__ float w1L[128 * 64];
  __shared__ float w2L[64];
  __shared__ float b1L[64];
  int b = blockIdx.y;
  int t = blockIdx.x * 128 + threadIdx.x;
  int tid = threadIdx.x;
  for (int i = tid; i < 128 * 64; i += 128) w1L[i] = w1[i];
  if (tid < 64) {
    w2L[tid] = w2[tid];
    b1L[tid] = b1[tid];
  }
  __syncthreads();
  float hid[64];
#pragma unroll
  for (int j = 0; j < 64; j++) hid[j] = b1L[j];
  const float* pv = &pooled[((size_t)b * 512 + t) * 128];
  for (int c = 0; c < 128; c++) {
    float xv = pv[c];
#pragma unroll
    for (int j = 0; j < 64; j++) hid[j] += xv * w1L[c * 64 + j];
  }
  float s = b2v[0];
#pragma unroll
  for (int j = 0; j < 64; j++) s += tanhf(hid[j]) * w2L[j];
  score[(size_t)b * 512 + t] = s;
}

// ---------------- softmax over T'=512 per sample ----------------------------
__global__ __launch_bounds__(256) void k_attn2(const float* __restrict__ score,
                                               float* __restrict__ wgt) {
  __shared__ float sc[512];
  __shared__ float red[4];
  int b = blockIdx.x;
  int tid = threadIdx.x;
  for (int t = tid; t < 512; t += 256) sc[t] = score[(size_t)b * 512 + t];
  __syncthreads();
  float mx = -1e30f;
  for (int t = tid; t < 512; t += 256) mx = fmaxf(mx, sc[t]);
  for (int off = 32; off; off >>= 1) mx = fmaxf(mx, __shfl_down(mx, off));
  if ((tid & 63) == 0) red[tid >> 6] = mx;
  __syncthreads();
  mx = fmaxf(fmaxf(red[0], red[1]), fmaxf(red[2], red[3]));
  __syncthreads();
  float sum = 0.f;
  for (int t = tid; t < 512; t += 256) {
    float e = expf(sc[t] - mx);
    sc[t] = e;
    sum += e;
  }
  for (int off = 32; off; off >>= 1) sum += __shfl_down(sum, off);
  if ((tid & 63) == 0) red[tid >> 6] = sum;
  __syncthreads();
  float inv = 1.f / (red[0] + red[1] + red[2] + red[3]);
  for (int t = tid; t < 512; t += 256) wgt[(size_t)b * 512 + t] = sc[t] * inv;
}

// ---------------- weighted feature chunks -----------------------------------
__global__ __launch_bounds__(256) void k_feat2(const float* __restrict__ pooled,
                                               const float* __restrict__ wgt,
                                               float* __restrict__ featb) {
  __shared__ float sh[16][17];
  int b = blockIdx.y;
  int c0 = blockIdx.x * 16;
  int cl = threadIdx.x & 15, tlane = threadIdx.x >> 4;  // 16 t-lanes
  float s = 0.f;
  for (int t = tlane; t < 512; t += 16)
    s += pooled[((size_t)b * 512 + t) * 128 + c0 + cl] * wgt[(size_t)b * 512 + t];
  sh[tlane][cl] = s;
  __syncthreads();
  if (threadIdx.x < 16) {
    float a = 0.f;
    for (int q = 0; q < 16; q++) a += sh[q][threadIdx.x];
    featb[(size_t)b * 128 + c0 + threadIdx.x] = a;
  }
}

// ---------------- logits ----------------------------------------------------
__global__ __launch_bounds__(128) void k_logits(const float* __restrict__ featb,
                                                const float* __restrict__ fcw,
                                                const float* __restrict__ fcb,
                                                float* __restrict__ out) {
  __shared__ float fL[128];
  int b = blockIdx.x;
  fL[threadIdx.x] = featb[(size_t)b * 128 + threadIdx.x];
  __syncthreads();
  if (threadIdx.x < 3) {
    float l = fcb[threadIdx.x];
    for (int cc = 0; cc < 128; cc++) l += fL[cc] * fcw[cc * 3 + threadIdx.x];
    out[(size_t)b * 3 + threadIdx.x] = l;
  }
}

// ============================================================================
extern "C" void kernel_launch(void* const* d_in, const int* in_sizes, int n_in,
                              void* d_out, int out_size, void* d_ws, size_t ws_size,
                              hipStream_t stream) {
  (void)in_sizes; (void)n_in; (void)out_size;
  const float* x = (const float*)d_in[0];
  const float* adj = (const float*)d_in[1];
  const float* gw0 = (const float*)d_in[2];
  const float* cw0 = (const float*)d_in[4];
  const float* rw0 = (const float*)d_in[6];
  const float* rb0 = (const float*)d_in[7];
  const float* gw1 = (const float*)d_in[8];
  const float* cw1 = (const float*)d_in[10];
  const float* rw1 = (const float*)d_in[12];
  const float* rb1 = (const float*)d_in[13];
  const float* gw2 = (const float*)d_in[14];
  const float* cw2 = (const float*)d_in[16];
  const float* rw2 = (const float*)d_in[18];
  const float* rb2 = (const float*)d_in[19];
  const float* aw1 = (const float*)d_in[20];
  const float* ab1 = (const float*)d_in[21];
  const float* aw2 = (const float*)d_in[22];
  const float* ab2 = (const float*)d_in[23];
  const float* fcw = (const float*)d_in[24];
  const float* fcb = (const float*)d_in[25];
  float* out = (float*)d_out;
  float* ws = (float*)d_ws;

  // ---- shared ws region ----
  float* a_norm = ws;                  // 3844
  float* wt0 = a_norm + 3844;          // 9216
  float* wt1 = wt0 + 9216;             // 36864
  float* wt2 = wt1 + 36864;            // 147456
  float* wrt0 = wt2 + 147456;          // 160
  float* wrt1 = wrt0 + 160;            // 2048
  float* wrt2 = wrt1 + 2048;           // 8192
  float* pooled = wrt2 + 8192;         // 32*512*128 = 2097152
  float* scoreb = pooled + 2097152;    // 16384
  float* wgtA = scoreb + 16384;        // 16384
  float* featb = wgtA + 16384;         // 4096
  float* chunk_base = featb + 4096;
  size_t shared_floats = (size_t)(chunk_base - ws);

  const size_t PS_BUF = 4063232;  // 128*62*512 == 64*62*1024
  const size_t per_sample = 3 * PS_BUF + 2 * 1024;

  size_t avail = ws_size / sizeof(float);
  long cap = 1;
  if (avail > shared_floats) cap = (long)((avail - shared_floats) / per_sample);
  int Bc = (int)cap;
  if (Bc < 1) Bc = 1;
  if (Bc > 32) Bc = 32;

  // one-time prep
  k_prep<<<dim3(1), dim3(256), 0, stream>>>(adj, a_norm, out + 96);
  k_wt<<<dim3(64), dim3(256), 0, stream>>>(cw0, wt0, 32, rw0, wrt0, 5);
  k_wt<<<dim3(160), dim3(256), 0, stream>>>(cw1, wt1, 64, rw1, wrt1, 32);
  k_wt<<<dim3(576), dim3(256), 0, stream>>>(cw2, wt2, 128, rw2, wrt2, 64);

  float* sp1 = chunk_base;                      // Bc*1024
  float* sp2 = sp1 + (size_t)Bc * 1024;         // Bc*1024
  float* B1 = sp2 + (size_t)Bc * 1024;
  float* B2 = B1 + (size_t)Bc * PS_BUF;
  float* B3 = B2 + (size_t)Bc * PS_BUF;

  for (int b0 = 0; b0 < 32; b0 += Bc) {
    int bc = (32 - b0 < Bc) ? (32 - b0) : Bc;

    // ---- block 0: 5 -> 32, T 1024, stride 1; in = x (global) ----
    k_spatial0<32><<<dim3(32, 2, bc), dim3(256), 0, stream>>>(x, a_norm, B2, b0);
    k_wmix<5, 32, 1024><<<dim3(496, bc), dim3(256), 0, stream>>>(B2, gw0, B3);
    k_statsP<<<dim3(32, NP, bc), dim3(256), 0, stream>>>(B3, sp1, 63488);
    k_conv<32, 1024, 1><<<dim3(16, NN, bc), dim3(256), 0, stream>>>(B3, wt0, sp1, B2);
    k_statsP<<<dim3(32, NP, bc), dim3(256), 0, stream>>>(B2, sp2, 63488);
    k_post<5, 32, 1024, 1, true><<<dim3(16, NN, bc), dim3(256), 0, stream>>>(
        B2, sp2, x, wrt0, rb0, B1, b0);  // A -> B1

    // ---- block 1: 32 -> 64, T 1024->512, stride 2; in = A (B1) ----
    k_spatial<32, 1024><<<dim3(8, 32, bc), dim3(256), 0, stream>>>(B1, a_norm, B3);
    k_wmix<32, 64, 1024><<<dim3(992, bc), dim3(256), 0, stream>>>(B3, gw1, B2);
    k_statsP<<<dim3(64, NP, bc), dim3(256), 0, stream>>>(B2, sp1, 63488);
    k_conv<64, 1024, 2><<<dim3(8, NN, bc), dim3(256), 0, stream>>>(B2, wt1, sp1, B3);
    k_statsP<<<dim3(64, NP, bc), dim3(256), 0, stream>>>(B3, sp2, 31744);
    k_post<32, 64, 512, 2, false><<<dim3(8, NN, bc), dim3(256), 0, stream>>>(
        B3, sp2, B1, wrt1, rb1, B2, b0);  // D -> B2

    // ---- block 2: 64 -> 128, T 512, stride 1; in = D (B2) ----
    k_spatial<64, 512><<<dim3(4, 64, bc), dim3(256), 0, stream>>>(B2, a_norm, B1);
    k_wmix<64, 128, 512><<<dim3(496, bc), dim3(256), 0, stream>>>(B1, gw2, B3);
    k_statsP<<<dim3(128, NP, bc), dim3(256), 0, stream>>>(B3, sp1, 31744);
    k_conv<128, 512, 1><<<dim3(8, NN, bc), dim3(256), 0, stream>>>(B3, wt2, sp1, B1);
    k_statsP<<<dim3(128, NP, bc), dim3(256), 0, stream>>>(B1, sp2, 31744);
    k_post<64, 128, 512, 1, false><<<dim3(8, NN, bc), dim3(256), 0, stream>>>(
        B1, sp2, B2, wrt2, rb2, B3, b0);  // out2 -> B3

    k_pool<<<dim3(8, 32, bc), dim3(256), 0, stream>>>(B3, pooled, b0);
  }

  // ---- head: full batch at once ----
  k_attn1<<<dim3(4, 32), dim3(128), 0, stream>>>(pooled, aw1, ab1, aw2, ab2, scoreb);
  k_attn2<<<dim3(32), dim3(256), 0, stream>>>(scoreb, wgtA);
  k_feat2<<<dim3(8, 32), dim3(256), 0, stream>>>(pooled, wgtA, featb);
  k_logits<<<dim3(32), dim3(128), 0, stream>>>(featb, fcw, fcb, out);
}

// Round 3
// 5171.369 us; speedup vs baseline: 3.8234x; 2.2872x over previous
//
#include <hip/hip_runtime.h>

// ST-GCN classifier forward. Round 3: temporal conv rewritten as bf16 MFMA
// GEMM (16x16x32), normalized input staged transposed in LDS (padded rows),
// per-tap weight tile in LDS. Everything else fp32 as in round 2 (passed).

#define NN 62
#define KK 9
#define NP 4  // stats partials

typedef short s16x8 __attribute__((ext_vector_type(8)));
typedef float f32x4 __attribute__((ext_vector_type(4)));

__device__ __forceinline__ unsigned short f2bf(float f) {
  unsigned u = __builtin_bit_cast(unsigned, f);
  u += 0x7FFF + ((u >> 16) & 1);
  return (unsigned short)(u >> 16);
}

// ---------------- prep: gcn-normalized adjacency + adj passthrough ----------
__global__ __launch_bounds__(256) void k_prep(const float* __restrict__ adj,
                                              float* __restrict__ a_norm,
                                              float* __restrict__ out_adj) {
  __shared__ float dinv[NN];
  int tid = threadIdx.x;
  if (tid < NN) {
    float s = 1.0f;  // self loop
    for (int n = 0; n < NN; n++) s += adj[tid * NN + n];
    dinv[tid] = (s > 0.f) ? rsqrtf(fmaxf(s, 1e-5f)) : 0.f;
  }
  __syncthreads();
  for (int idx = tid; idx < NN * NN; idx += 256) {
    int m = idx / NN, n = idx - m * NN;
    float ah = adj[idx] + ((m == n) ? 1.f : 0.f);
    a_norm[idx] = dinv[m] * ah * dinv[n];
    out_adj[idx] = adj[idx];
  }
}

// ------------- weight prep: conv [o][ci][k] -> bf16 [k][o][ci]; res [o][ci]->[ci][o]
__global__ __launch_bounds__(256) void k_wt(const float* __restrict__ wc,
                                            unsigned short* __restrict__ wkb, int C,
                                            const float* __restrict__ wr,
                                            float* __restrict__ wrt, int CIN) {
  int stride = gridDim.x * blockDim.x;
  int total = C * C * KK;
  for (int i = blockIdx.x * blockDim.x + threadIdx.x; i < total; i += stride) {
    int o = i / (C * KK);
    int r = i - o * C * KK;
    int ci = r / KK;
    int k = r - ci * KK;
    wkb[((size_t)k * C + o) * C + ci] = f2bf(wc[i]);
  }
  int t2 = C * CIN;
  for (int i = blockIdx.x * blockDim.x + threadIdx.x; i < t2; i += stride) {
    int o = i / CIN, ci = i - o * CIN;
    wrt[ci * C + o] = wr[i];
  }
}

// ---------------- block-0 spatial: coalesced (t,f) reads of x ---------------
template <int TT>
__global__ __launch_bounds__(256) void k_spatial0(const float* __restrict__ x,
                                                  const float* __restrict__ a_norm,
                                                  float* __restrict__ xs, int b0) {
  constexpr int CIN = 5, TIN = 1024;
  constexpr int ROW = TT * CIN;
  __shared__ float xt[NN * ROW];
  __shared__ float aL[NN * NN];
  int t0 = blockIdx.x * TT;
  int mh = blockIdx.y;
  int bl = blockIdx.z;
  int tid = threadIdx.x;
  for (int i = tid; i < NN * NN; i += 256) aL[i] = a_norm[i];
  for (int i = tid; i < NN * ROW; i += 256) {
    int n = i / ROW, r = i - n * ROW;
    xt[i] = x[((size_t)((b0 + bl) * NN + n) * TIN + t0) * CIN + r];
  }
  __syncthreads();
  int m0 = mh * 31;
  for (int task = tid; task < CIN * 31 * TT; task += 256) {
    int f = task / (31 * TT);
    int rem = task - f * (31 * TT);
    int mi = rem / TT;
    int tl = rem - mi * TT;
    int m = m0 + mi;
    float acc = 0.f;
    for (int n = 0; n < NN; n++) acc += aL[m * NN + n] * xt[n * ROW + tl * CIN + f];
    xs[(((size_t)bl * CIN + f) * NN + m) * TIN + t0 + tl] = acc;
  }
}

// ---------------- generic spatial mix (chunk-local (b,f,n,t) input) ---------
template <int CIN, int TIN>
__global__ __launch_bounds__(256) void k_spatial(const float* __restrict__ in,
                                                 const float* __restrict__ a_norm,
                                                 float* __restrict__ xs) {
  constexpr int TT = 128;
  constexpr int RS = TT + 4;
  __shared__ float tile[NN * RS];
  __shared__ float aL[NN * NN];
  int t0 = blockIdx.x * TT;
  int f = blockIdx.y;
  int bl = blockIdx.z;
  int tid = threadIdx.x;
  for (int i = tid; i < NN * NN; i += 256) aL[i] = a_norm[i];
  for (int i = tid; i < NN * TT; i += 256) {
    int n = i / TT, tl = i - n * TT;
    tile[n * RS + tl] = in[(((size_t)bl * CIN + f) * NN + n) * TIN + t0 + tl];
  }
  __syncthreads();
  constexpr int T4 = TT / 4;
  for (int task = tid; task < NN * T4; task += 256) {
    int m = task / T4;
    int t4 = (task - m * T4) * 4;
    float4 acc = {0.f, 0.f, 0.f, 0.f};
    for (int n = 0; n < NN; n++) {
      float av = aL[m * NN + n];
      float4 xv = *reinterpret_cast<const float4*>(&tile[n * RS + t4]);
      acc.x += av * xv.x;
      acc.y += av * xv.y;
      acc.z += av * xv.z;
      acc.w += av * xv.w;
    }
    *reinterpret_cast<float4*>(&xs[(((size_t)bl * CIN + f) * NN + m) * TIN + t0 + t4]) = acc;
  }
}

// ---------------- channel mix: y[b,o,s] = sum_f wg[f,o] * xs[b,f,s] ---------
template <int CIN, int COUT, int TIN>
__global__ __launch_bounds__(256) void k_wmix(const float* __restrict__ xs,
                                              const float* __restrict__ wg,
                                              float* __restrict__ y) {
  constexpr int S = NN * TIN;
  constexpr int O4L = (COUT / 4 < 16) ? COUT / 4 : 16;
  constexpr int SL = 256 / O4L;
  constexpr int ST = SL * 4;
  constexpr int RS = ST + 4;
  __shared__ float xt[CIN * RS];
  __shared__ float wL[CIN * COUT];
  int s0 = blockIdx.x * ST;
  int bl = blockIdx.y;
  int tid = threadIdx.x;
  for (int i = tid; i < CIN * COUT; i += 256) wL[i] = wg[i];
  for (int i = tid; i < CIN * ST; i += 256) {
    int f = i / ST, sl = i - f * ST;
    xt[f * RS + sl] = xs[((size_t)bl * CIN + f) * S + s0 + sl];
  }
  __syncthreads();
  int s4 = (tid % SL) * 4;
  int o4l = tid / SL;
  constexpr int PASSES = COUT / (4 * O4L);
  for (int op = 0; op < PASSES; op++) {
    int o0 = op * (4 * O4L) + o4l * 4;
    float4 a0 = {0, 0, 0, 0}, a1 = {0, 0, 0, 0}, a2 = {0, 0, 0, 0}, a3 = {0, 0, 0, 0};
    for (int f = 0; f < CIN; f++) {
      float4 xv = *reinterpret_cast<const float4*>(&xt[f * RS + s4]);
      float4 wv = *reinterpret_cast<const float4*>(&wL[f * COUT + o0]);
      a0.x += wv.x * xv.x; a0.y += wv.x * xv.y; a0.z += wv.x * xv.z; a0.w += wv.x * xv.w;
      a1.x += wv.y * xv.x; a1.y += wv.y * xv.y; a1.z += wv.y * xv.z; a1.w += wv.y * xv.w;
      a2.x += wv.z * xv.x; a2.y += wv.z * xv.y; a2.z += wv.z * xv.z; a2.w += wv.z * xv.w;
      a3.x += wv.w * xv.x; a3.y += wv.w * xv.y; a3.z += wv.w * xv.z; a3.w += wv.w * xv.w;
    }
    *reinterpret_cast<float4*>(&y[((size_t)bl * COUT + o0 + 0) * S + s0 + s4]) = a0;
    *reinterpret_cast<float4*>(&y[((size_t)bl * COUT + o0 + 1) * S + s0 + s4]) = a1;
    *reinterpret_cast<float4*>(&y[((size_t)bl * COUT + o0 + 2) * S + s0 + s4]) = a2;
    *reinterpret_cast<float4*>(&y[((size_t)bl * COUT + o0 + 3) * S + s0 + s4]) = a3;
  }
}

// ---------------- per-(b,c) stats partials: sum, sumsq over S/NP ------------
__global__ __launch_bounds__(256) void k_statsP(const float* __restrict__ src,
                                                float* __restrict__ part, int S) {
  int c = blockIdx.x, p = blockIdx.y, bl = blockIdx.z;
  int C = gridDim.x;
  int chunkS = S / NP;
  int s0 = p * chunkS;
  const float* q = src + ((size_t)bl * C + c) * S;
  float s = 0.f, s2 = 0.f;
  for (int i = s0 + threadIdx.x; i < s0 + chunkS; i += 256) {
    float v = q[i];
    s += v;
    s2 += v * v;
  }
  for (int off = 32; off; off >>= 1) {
    s += __shfl_down(s, off);
    s2 += __shfl_down(s2, off);
  }
  __shared__ float ls[4], ls2[4];
  int w = threadIdx.x >> 6;
  if ((threadIdx.x & 63) == 0) {
    ls[w] = s;
    ls2[w] = s2;
  }
  __syncthreads();
  if (threadIdx.x == 0) {
    size_t o = (((size_t)bl * C + c) * NP + p) * 2;
    part[o + 0] = ls[0] + ls[1] + ls[2] + ls[3];
    part[o + 1] = ls2[0] + ls2[1] + ls2[2] + ls2[3];
  }
}

// finalize partials -> (mean, rsigma) into stL[2*C]
template <int C, int S>
__device__ __forceinline__ void finalize_stats(const float* __restrict__ part, int bl,
                                               float* __restrict__ stL, int tid) {
  for (int c = tid; c < C; c += 256) {
    float s = 0.f, s2 = 0.f;
#pragma unroll
    for (int p = 0; p < NP; p++) {
      size_t o = (((size_t)bl * C + c) * NP + p) * 2;
      s += part[o];
      s2 += part[o + 1];
    }
    float m = s / (float)S;
    float v = s2 / (float)S - m * m;
    stL[2 * c] = m;
    stL[2 * c + 1] = rsqrtf(fmaxf(v, 0.f) + 1e-5f);
  }
}

// ---------------- temporal conv as bf16 MFMA GEMM ---------------------------
// c[o,n,t'] = sum_{ci,k} wk[k][o][ci] * relu(IN(y))[ci, n, STRIDE*t'+k-4]
template <int C, int TIN, int STRIDE, int BN>
__global__ __launch_bounds__(256) void k_convmma(const float* __restrict__ y,
                                                 const unsigned short* __restrict__ wkb,
                                                 const float* __restrict__ part,
                                                 float* __restrict__ cbuf) {
  constexpr int TOUT = TIN / STRIDE;
  constexpr int SPAN = STRIDE * BN + 8;   // input t-span incl. halo
  constexpr int CP = C + 8;               // padded row (bf16 elems): +16B kills conflicts
  constexpr int WM = (C >= 64) ? 2 : 1;   // wave grid
  constexpr int WN = 4 / WM;
  constexpr int MF = C / (16 * WM);       // 16-row M-frags per wave
  constexpr int NF = BN / (16 * WN);      // 16-col N-frags per wave

  __shared__ unsigned short zt[SPAN * CP];  // transposed normalized input [t][ci]
  __shared__ unsigned short wl[C * CP];     // per-tap weights [o][ci]
  __shared__ float stL[2 * C];

  int t0 = blockIdx.x * BN;
  int n = blockIdx.y;
  int bl = blockIdx.z;
  int tid = threadIdx.x;
  int tin0 = STRIDE * t0 - 4;

  finalize_stats<C, NN * TIN>(part, bl, stL, tid);
  __syncthreads();

  // stage normalized+relu input, transposed, bf16
  for (int i = tid; i < C * SPAN; i += 256) {
    int ci = i / SPAN, r = i - ci * SPAN;
    int t = tin0 + r;
    float v = 0.f;
    if (t >= 0 && t < TIN)
      v = fmaxf((y[(((size_t)bl * C + ci) * NN + n) * TIN + t] - stL[2 * ci]) * stL[2 * ci + 1], 0.f);
    zt[r * CP + ci] = f2bf(v);
  }

  int w = tid >> 6;
  int lane = tid & 63;
  int lm = lane & 15, kh = lane >> 4;
  int o0w = (w / WN) * (C / WM);
  int col0 = (w % WN) * (BN / WN);

  f32x4 acc[MF][NF];
#pragma unroll
  for (int mf = 0; mf < MF; mf++)
#pragma unroll
    for (int nf = 0; nf < NF; nf++) acc[mf][nf] = (f32x4){0.f, 0.f, 0.f, 0.f};

  for (int k = 0; k < KK; k++) {
    __syncthreads();  // prior k's reads done (k=0: covers zt staging)
    const unsigned short* wg = wkb + (size_t)k * C * C;
    for (int i = tid * 4; i < C * C; i += 1024) {
      int o = i / C, ci = i - o * C;
      *reinterpret_cast<ushort4*>(&wl[o * CP + ci]) =
          *reinterpret_cast<const ushort4*>(&wg[i]);
    }
    __syncthreads();
#pragma unroll
    for (int ci0 = 0; ci0 < C; ci0 += 32) {
      s16x8 a[MF], b[NF];
#pragma unroll
      for (int mf = 0; mf < MF; mf++)
        a[mf] = *reinterpret_cast<const s16x8*>(&wl[(o0w + mf * 16 + lm) * CP + ci0 + kh * 8]);
#pragma unroll
      for (int nf = 0; nf < NF; nf++) {
        int col = col0 + nf * 16 + lm;
        int r = STRIDE * col + k;
        b[nf] = *reinterpret_cast<const s16x8*>(&zt[r * CP + ci0 + kh * 8]);
      }
#pragma unroll
      for (int mf = 0; mf < MF; mf++)
#pragma unroll
        for (int nf = 0; nf < NF; nf++)
          acc[mf][nf] = __builtin_amdgcn_mfma_f32_16x16x32_bf16(a[mf], b[nf], acc[mf][nf], 0, 0, 0);
    }
  }

  // epilogue: D[row=(l>>4)*4+r][col=l&15]
#pragma unroll
  for (int mf = 0; mf < MF; mf++)
#pragma unroll
    for (int nf = 0; nf < NF; nf++) {
      int tp = t0 + col0 + nf * 16 + lm;
#pragma unroll
      for (int rr = 0; rr < 4; rr++) {
        int o = o0w + mf * 16 + kh * 4 + rr;
        cbuf[(((size_t)bl * C + o) * NN + n) * TOUT + tp] = acc[mf][nf][rr];
      }
    }
}

// ------- epilogue: out = relu( relu((c-m2)*rs2) + res(in) + br ) ------------
template <int CIN, int COUT, int TOUT, int STRIDE, bool LAYX>
__global__ __launch_bounds__(256) void k_post(const float* __restrict__ cbuf,
                                              const float* __restrict__ part,
                                              const float* __restrict__ in,
                                              const float* __restrict__ wrt,
                                              const float* __restrict__ br,
                                              float* __restrict__ out, int b0) {
  constexpr int TT = 64;
  constexpr int TIN_ = TOUT * STRIDE;
  __shared__ float inT[CIN * TT];
  __shared__ float wL[CIN * COUT];
  __shared__ float brL[COUT];
  __shared__ float stL[2 * COUT];
  int t0 = blockIdx.x * TT, n = blockIdx.y, bl = blockIdx.z;
  int tid = threadIdx.x;
  for (int i = tid; i < CIN * COUT; i += 256) wL[i] = wrt[i];
  if (tid < COUT) brL[tid] = br[tid];
  finalize_stats<COUT, NN * TOUT>(part, bl, stL, tid);
  for (int i = tid; i < CIN * TT; i += 256) {
    int ci = i / TT, tl = i - ci * TT;
    int t = STRIDE * (t0 + tl);
    float v;
    if (LAYX)
      v = in[(((size_t)(b0 + bl) * NN + n) * TIN_ + t) * CIN + ci];
    else
      v = in[(((size_t)bl * CIN + ci) * NN + n) * TIN_ + t];
    inT[i] = v;
  }
  __syncthreads();
  int tl = tid & 63;
  int o4 = tid >> 6;
  int t = t0 + tl;
  for (int op = 0; op < COUT / 16; op++) {
    int o0 = op * 16 + o4 * 4;
    float accA[4] = {0.f, 0.f, 0.f, 0.f};
    for (int ci = 0; ci < CIN; ci++) {
      float xv = inT[ci * TT + tl];
      float4 wv = *reinterpret_cast<const float4*>(&wL[ci * COUT + o0]);
      accA[0] += wv.x * xv;
      accA[1] += wv.y * xv;
      accA[2] += wv.z * xv;
      accA[3] += wv.w * xv;
    }
#pragma unroll
    for (int q = 0; q < 4; q++) {
      int o = o0 + q;
      float m = stL[2 * o], rs = stL[2 * o + 1];
      float cv = cbuf[(((size_t)bl * COUT + o) * NN + n) * TOUT + t];
      float v = fmaxf((cv - m) * rs, 0.f) + accA[q] + brL[o];
      out[(((size_t)bl * COUT + o) * NN + n) * TOUT + t] = fmaxf(v, 0.f);
    }
  }
}

// ---------------- node-mean pool: pooled[b0+b,t,c] = mean_n src[b,c,n,t] ----
__global__ __launch_bounds__(256) void k_pool(const float* __restrict__ src,
                                              float* __restrict__ pooled, int b0) {
  constexpr int CP = 128, TPZ = 512;
  int t = blockIdx.x * 64 + (threadIdx.x & 63);
  int c = blockIdx.y * 4 + (threadIdx.x >> 6);
  int bl = blockIdx.z;
  const float* p = src + ((size_t)bl * CP + c) * NN * TPZ + t;
  float s = 0.f;
  for (int n = 0; n < NN; n++) s += p[(size_t)n * TPZ];
  pooled[((size_t)(b0 + bl) * TPZ + t) * CP + c] = s * (1.f / NN);
}

// ---------------- attention scores (full batch) -----------------------------
__global__ __launch_bounds__(128) void k_attn1(const float* __restrict__ pooled,
                                               const float* __restrict__ w1,
                                               const float* __restrict__ b1,
                                               const float* __restrict__ w2,
                                               const float* __restrict__ b2v,
                                               float* __restrict__ score) {
  __shared__ float w1L[128 * 64];
  __shared__ float w2L[64];
  __shared__ float b1L[64];
  int b = blockIdx.y;
  int t = blockIdx.x * 128 + threadIdx.x;
  int tid = threadIdx.x;
  for (int i = tid; i < 128 * 64; i += 128) w1L[i] = w1[i];
  if (tid < 64) {
    w2L[tid] = w2[tid];
    b1L[tid] = b1[tid];
  }
  __syncthreads();
  float hid[64];
#pragma unroll
  for (int j = 0; j < 64; j++) hid[j] = b1L[j];
  const float* pv = &pooled[((size_t)b * 512 + t) * 128];
  for (int c = 0; c < 128; c++) {
    float xv = pv[c];
#pragma unroll
    for (int j = 0; j < 64; j++) hid[j] += xv * w1L[c * 64 + j];
  }
  float s = b2v[0];
#pragma unroll
  for (int j = 0; j < 64; j++) s += tanhf(hid[j]) * w2L[j];
  score[(size_t)b * 512 + t] = s;
}

// ---------------- softmax over T'=512 per sample ----------------------------
__global__ __launch_bounds__(256) void k_attn2(const float* __restrict__ score,
                                               float* __restrict__ wgt) {
  __shared__ float sc[512];
  __shared__ float red[4];
  int b = blockIdx.x;
  int tid = threadIdx.x;
  for (int t = tid; t < 512; t += 256) sc[t] = score[(size_t)b * 512 + t];
  __syncthreads();
  float mx = -1e30f;
  for (int t = tid; t < 512; t += 256) mx = fmaxf(mx, sc[t]);
  for (int off = 32; off; off >>= 1) mx = fmaxf(mx, __shfl_down(mx, off));
  if ((tid & 63) == 0) red[tid >> 6] = mx;
  __syncthreads();
  mx = fmaxf(fmaxf(red[0], red[1]), fmaxf(red[2], red[3]));
  __syncthreads();
  float sum = 0.f;
  for (int t = tid; t < 512; t += 256) {
    float e = expf(sc[t] - mx);
    sc[t] = e;
    sum += e;
  }
  for (int off = 32; off; off >>= 1) sum += __shfl_down(sum, off);
  if ((tid & 63) == 0) red[tid >> 6] = sum;
  __syncthreads();
  float inv = 1.f / (red[0] + red[1] + red[2] + red[3]);
  for (int t = tid; t < 512; t += 256) wgt[(size_t)b * 512 + t] = sc[t] * inv;
}

// ---------------- weighted feature chunks -----------------------------------
__global__ __launch_bounds__(256) void k_feat2(const float* __restrict__ pooled,
                                               const float* __restrict__ wgt,
                                               float* __restrict__ featb) {
  __shared__ float sh[16][17];
  int b = blockIdx.y;
  int c0 = blockIdx.x * 16;
  int cl = threadIdx.x & 15, tlane = threadIdx.x >> 4;
  float s = 0.f;
  for (int t = tlane; t < 512; t += 16)
    s += pooled[((size_t)b * 512 + t) * 128 + c0 + cl] * wgt[(size_t)b * 512 + t];
  sh[tlane][cl] = s;
  __syncthreads();
  if (threadIdx.x < 16) {
    float a = 0.f;
    for (int q = 0; q < 16; q++) a += sh[q][threadIdx.x];
    featb[(size_t)b * 128 + c0 + threadIdx.x] = a;
  }
}

// ---------------- logits ----------------------------------------------------
__global__ __launch_bounds__(128) void k_logits(const float* __restrict__ featb,
                                                const float* __restrict__ fcw,
                                                const float* __restrict__ fcb,
                                                float* __restrict__ out) {
  __shared__ float fL[128];
  int b = blockIdx.x;
  fL[threadIdx.x] = featb[(size_t)b * 128 + threadIdx.x];
  __syncthreads();
  if (threadIdx.x < 3) {
    float l = fcb[threadIdx.x];
    for (int cc = 0; cc < 128; cc++) l += fL[cc] * fcw[cc * 3 + threadIdx.x];
    out[(size_t)b * 3 + threadIdx.x] = l;
  }
}

// ============================================================================
extern "C" void kernel_launch(void* const* d_in, const int* in_sizes, int n_in,
                              void* d_out, int out_size, void* d_ws, size_t ws_size,
                              hipStream_t stream) {
  (void)in_sizes; (void)n_in; (void)out_size;
  const float* x = (const float*)d_in[0];
  const float* adj = (const float*)d_in[1];
  const float* gw0 = (const float*)d_in[2];
  const float* cw0 = (const float*)d_in[4];
  const float* rw0 = (const float*)d_in[6];
  const float* rb0 = (const float*)d_in[7];
  const float* gw1 = (const float*)d_in[8];
  const float* cw1 = (const float*)d_in[10];
  const float* rw1 = (const float*)d_in[12];
  const float* rb1 = (const float*)d_in[13];
  const float* gw2 = (const float*)d_in[14];
  const float* cw2 = (const float*)d_in[16];
  const float* rw2 = (const float*)d_in[18];
  const float* rb2 = (const float*)d_in[19];
  const float* aw1 = (const float*)d_in[20];
  const float* ab1 = (const float*)d_in[21];
  const float* aw2 = (const float*)d_in[22];
  const float* ab2 = (const float*)d_in[23];
  const float* fcw = (const float*)d_in[24];
  const float* fcb = (const float*)d_in[25];
  float* out = (float*)d_out;
  float* ws = (float*)d_ws;

  // ---- shared ws region (sizes in floats) ----
  float* a_norm = ws;                        // 3844
  unsigned short* wk0 = (unsigned short*)(a_norm + 3844);  // 9216 u16 = 4608 f
  unsigned short* wk1 = (unsigned short*)(a_norm + 3844 + 4608);   // 36864 u16 = 18432 f
  unsigned short* wk2 = (unsigned short*)(a_norm + 3844 + 4608 + 18432);  // 147456 u16 = 73728 f
  float* wrt0 = a_norm + 3844 + 4608 + 18432 + 73728;  // 160
  float* wrt1 = wrt0 + 160;                  // 2048
  float* wrt2 = wrt1 + 2048;                 // 8192
  float* pooled = wrt2 + 8192;               // 32*512*128 = 2097152
  float* scoreb = pooled + 2097152;          // 16384
  float* wgtA = scoreb + 16384;              // 16384
  float* featb = wgtA + 16384;               // 4096
  float* chunk_base = featb + 4096;
  size_t shared_floats = (size_t)(chunk_base - ws);

  const size_t PS_BUF = 4063232;  // 128*62*512 == 64*62*1024
  const size_t per_sample = 3 * PS_BUF + 2 * 1024;

  size_t avail = ws_size / sizeof(float);
  long cap = 1;
  if (avail > shared_floats) cap = (long)((avail - shared_floats) / per_sample);
  int Bc = (int)cap;
  if (Bc < 1) Bc = 1;
  if (Bc > 32) Bc = 32;

  // one-time prep
  k_prep<<<dim3(1), dim3(256), 0, stream>>>(adj, a_norm, out + 96);
  k_wt<<<dim3(64), dim3(256), 0, stream>>>(cw0, wk0, 32, rw0, wrt0, 5);
  k_wt<<<dim3(160), dim3(256), 0, stream>>>(cw1, wk1, 64, rw1, wrt1, 32);
  k_wt<<<dim3(576), dim3(256), 0, stream>>>(cw2, wk2, 128, rw2, wrt2, 64);

  float* sp1 = chunk_base;                      // Bc*1024
  float* sp2 = sp1 + (size_t)Bc * 1024;         // Bc*1024
  float* B1 = sp2 + (size_t)Bc * 1024;
  float* B2 = B1 + (size_t)Bc * PS_BUF;
  float* B3 = B2 + (size_t)Bc * PS_BUF;

  for (int b0 = 0; b0 < 32; b0 += Bc) {
    int bc = (32 - b0 < Bc) ? (32 - b0) : Bc;

    // ---- block 0: 5 -> 32, T 1024, stride 1; in = x (global) ----
    k_spatial0<32><<<dim3(32, 2, bc), dim3(256), 0, stream>>>(x, a_norm, B2, b0);
    k_wmix<5, 32, 1024><<<dim3(496, bc), dim3(256), 0, stream>>>(B2, gw0, B3);
    k_statsP<<<dim3(32, NP, bc), dim3(256), 0, stream>>>(B3, sp1, 63488);
    k_convmma<32, 1024, 1, 256><<<dim3(4, NN, bc), dim3(256), 0, stream>>>(B3, wk0, sp1, B2);
    k_statsP<<<dim3(32, NP, bc), dim3(256), 0, stream>>>(B2, sp2, 63488);
    k_post<5, 32, 1024, 1, true><<<dim3(16, NN, bc), dim3(256), 0, stream>>>(
        B2, sp2, x, wrt0, rb0, B1, b0);  // A -> B1

    // ---- block 1: 32 -> 64, T 1024->512, stride 2; in = A (B1) ----
    k_spatial<32, 1024><<<dim3(8, 32, bc), dim3(256), 0, stream>>>(B1, a_norm, B3);
    k_wmix<32, 64, 1024><<<dim3(992, bc), dim3(256), 0, stream>>>(B3, gw1, B2);
    k_statsP<<<dim3(64, NP, bc), dim3(256), 0, stream>>>(B2, sp1, 63488);
    k_convmma<64, 1024, 2, 128><<<dim3(4, NN, bc), dim3(256), 0, stream>>>(B2, wk1, sp1, B3);
    k_statsP<<<dim3(64, NP, bc), dim3(256), 0, stream>>>(B3, sp2, 31744);
    k_post<32, 64, 512, 2, false><<<dim3(8, NN, bc), dim3(256), 0, stream>>>(
        B3, sp2, B1, wrt1, rb1, B2, b0);  // D -> B2

    // ---- block 2: 64 -> 128, T 512, stride 1; in = D (B2) ----
    k_spatial<64, 512><<<dim3(4, 64, bc), dim3(256), 0, stream>>>(B2, a_norm, B1);
    k_wmix<64, 128, 512><<<dim3(496, bc), dim3(256), 0, stream>>>(B1, gw2, B3);
    k_statsP<<<dim3(128, NP, bc), dim3(256), 0, stream>>>(B3, sp1, 31744);
    k_convmma<128, 512, 1, 128><<<dim3(4, NN, bc), dim3(256), 0, stream>>>(B3, wk2, sp1, B1);
    k_statsP<<<dim3(128, NP, bc), dim3(256), 0, stream>>>(B1, sp2, 31744);
    k_post<64, 128, 512, 1, false><<<dim3(8, NN, bc), dim3(256), 0, stream>>>(
        B1, sp2, B2, wrt2, rb2, B3, b0);  // out2 -> B3

    k_pool<<<dim3(8, 32, bc), dim3(256), 0, stream>>>(B3, pooled, b0);
  }

  // ---- head: full batch at once ----
  k_attn1<<<dim3(4, 32), dim3(128), 0, stream>>>(pooled, aw1, ab1, aw2, ab2, scoreb);
  k_attn2<<<dim3(32), dim3(256), 0, stream>>>(scoreb, wgtA);
  k_feat2<<<dim3(8, 32), dim3(256), 0, stream>>>(pooled, wgtA, featb);
  k_logits<<<dim3(32), dim3(128), 0, stream>>>(featb, fcw, fcb, out);
}

// Round 4
// 3567.525 us; speedup vs baseline: 5.5423x; 1.4496x over previous
//
#include <hip/hip_runtime.h>

// ST-GCN classifier forward. Round 4: bf16 intermediates (xs, y), conv with
// register-prefetch weight double-buffering + vectorized bf16 staging.
// cbuf/block-outputs stay fp32 (residual trunk accuracy).

#define NN 62
#define KK 9
#define NP 4  // stats partials

typedef short s16x8 __attribute__((ext_vector_type(8)));
typedef float f32x4 __attribute__((ext_vector_type(4)));

__device__ __forceinline__ unsigned short f2bf(float f) {
  unsigned u = __builtin_bit_cast(unsigned, f);
  u += 0x7FFF + ((u >> 16) & 1);
  return (unsigned short)(u >> 16);
}
__device__ __forceinline__ float bf2f(unsigned short u) {
  unsigned v = ((unsigned)u) << 16;
  return __builtin_bit_cast(float, v);
}
__device__ __forceinline__ ushort4 pack4(float4 a) {
  return (ushort4){f2bf(a.x), f2bf(a.y), f2bf(a.z), f2bf(a.w)};
}

// ---------------- prep: gcn-normalized adjacency + adj passthrough ----------
__global__ __launch_bounds__(256) void k_prep(const float* __restrict__ adj,
                                              float* __restrict__ a_norm,
                                              float* __restrict__ out_adj) {
  __shared__ float dinv[NN];
  int tid = threadIdx.x;
  if (tid < NN) {
    float s = 1.0f;  // self loop
    for (int n = 0; n < NN; n++) s += adj[tid * NN + n];
    dinv[tid] = (s > 0.f) ? rsqrtf(fmaxf(s, 1e-5f)) : 0.f;
  }
  __syncthreads();
  for (int idx = tid; idx < NN * NN; idx += 256) {
    int m = idx / NN, n = idx - m * NN;
    float ah = adj[idx] + ((m == n) ? 1.f : 0.f);
    a_norm[idx] = dinv[m] * ah * dinv[n];
    out_adj[idx] = adj[idx];
  }
}

// ------------- weight prep: conv [o][ci][k] -> bf16 [k][o][ci]; res [o][ci]->[ci][o]
__global__ __launch_bounds__(256) void k_wt(const float* __restrict__ wc,
                                            unsigned short* __restrict__ wkb, int C,
                                            const float* __restrict__ wr,
                                            float* __restrict__ wrt, int CIN) {
  int stride = gridDim.x * blockDim.x;
  int total = C * C * KK;
  for (int i = blockIdx.x * blockDim.x + threadIdx.x; i < total; i += stride) {
    int o = i / (C * KK);
    int r = i - o * C * KK;
    int ci = r / KK;
    int k = r - ci * KK;
    wkb[((size_t)k * C + o) * C + ci] = f2bf(wc[i]);
  }
  int t2 = C * CIN;
  for (int i = blockIdx.x * blockDim.x + threadIdx.x; i < t2; i += stride) {
    int o = i / CIN, ci = i - o * CIN;
    wrt[ci * C + o] = wr[i];
  }
}

// ---------------- block-0 spatial: coalesced (t,f) reads of x ---------------
template <int TT>
__global__ __launch_bounds__(256) void k_spatial0(const float* __restrict__ x,
                                                  const float* __restrict__ a_norm,
                                                  unsigned short* __restrict__ xs, int b0) {
  constexpr int CIN = 5, TIN = 1024;
  constexpr int ROW = TT * CIN;
  __shared__ float xt[NN * ROW];
  __shared__ float aL[NN * NN];
  int t0 = blockIdx.x * TT;
  int mh = blockIdx.y;
  int bl = blockIdx.z;
  int tid = threadIdx.x;
  for (int i = tid; i < NN * NN; i += 256) aL[i] = a_norm[i];
  for (int i = tid; i < NN * ROW; i += 256) {
    int n = i / ROW, r = i - n * ROW;
    xt[i] = x[((size_t)((b0 + bl) * NN + n) * TIN + t0) * CIN + r];
  }
  __syncthreads();
  int m0 = mh * 31;
  for (int task = tid; task < CIN * 31 * TT; task += 256) {
    int f = task / (31 * TT);
    int rem = task - f * (31 * TT);
    int mi = rem / TT;
    int tl = rem - mi * TT;
    int m = m0 + mi;
    float acc = 0.f;
    for (int n = 0; n < NN; n++) acc += aL[m * NN + n] * xt[n * ROW + tl * CIN + f];
    xs[(((size_t)bl * CIN + f) * NN + m) * TIN + t0 + tl] = f2bf(acc);
  }
}

// ---------------- generic spatial mix: fp32 in, bf16 out --------------------
template <int CIN, int TIN>
__global__ __launch_bounds__(256) void k_spatial(const float* __restrict__ in,
                                                 const float* __restrict__ a_norm,
                                                 unsigned short* __restrict__ xs) {
  constexpr int TT = 128;
  constexpr int RS = TT + 4;
  __shared__ float tile[NN * RS];
  __shared__ float aL[NN * NN];
  int t0 = blockIdx.x * TT;
  int f = blockIdx.y;
  int bl = blockIdx.z;
  int tid = threadIdx.x;
  for (int i = tid; i < NN * NN; i += 256) aL[i] = a_norm[i];
  for (int i = tid; i < NN * TT; i += 256) {
    int n = i / TT, tl = i - n * TT;
    tile[n * RS + tl] = in[(((size_t)bl * CIN + f) * NN + n) * TIN + t0 + tl];
  }
  __syncthreads();
  constexpr int T4 = TT / 4;
  for (int task = tid; task < NN * T4; task += 256) {
    int m = task / T4;
    int t4 = (task - m * T4) * 4;
    float4 acc = {0.f, 0.f, 0.f, 0.f};
    for (int n = 0; n < NN; n++) {
      float av = aL[m * NN + n];
      float4 xv = *reinterpret_cast<const float4*>(&tile[n * RS + t4]);
      acc.x += av * xv.x;
      acc.y += av * xv.y;
      acc.z += av * xv.z;
      acc.w += av * xv.w;
    }
    *reinterpret_cast<ushort4*>(&xs[(((size_t)bl * CIN + f) * NN + m) * TIN + t0 + t4]) = pack4(acc);
  }
}

// ---------------- channel mix: bf16 in, bf16 out ----------------------------
template <int CIN, int COUT, int TIN>
__global__ __launch_bounds__(256) void k_wmix(const unsigned short* __restrict__ xs,
                                              const float* __restrict__ wg,
                                              unsigned short* __restrict__ y) {
  constexpr int S = NN * TIN;
  constexpr int O4L = (COUT / 4 < 16) ? COUT / 4 : 16;
  constexpr int SL = 256 / O4L;
  constexpr int ST = SL * 4;
  constexpr int RS = ST + 4;
  __shared__ float xt[CIN * RS];
  __shared__ float wL[CIN * COUT];
  int s0 = blockIdx.x * ST;
  int bl = blockIdx.y;
  int tid = threadIdx.x;
  for (int i = tid; i < CIN * COUT; i += 256) wL[i] = wg[i];
  for (int i = tid * 4; i < CIN * ST; i += 1024) {
    int f = i / ST, sl = i - f * ST;
    ushort4 u = *reinterpret_cast<const ushort4*>(&xs[((size_t)bl * CIN + f) * S + s0 + sl]);
    xt[f * RS + sl + 0] = bf2f(u.x);
    xt[f * RS + sl + 1] = bf2f(u.y);
    xt[f * RS + sl + 2] = bf2f(u.z);
    xt[f * RS + sl + 3] = bf2f(u.w);
  }
  __syncthreads();
  int s4 = (tid % SL) * 4;
  int o4l = tid / SL;
  constexpr int PASSES = COUT / (4 * O4L);
  for (int op = 0; op < PASSES; op++) {
    int o0 = op * (4 * O4L) + o4l * 4;
    float4 a0 = {0, 0, 0, 0}, a1 = {0, 0, 0, 0}, a2 = {0, 0, 0, 0}, a3 = {0, 0, 0, 0};
    for (int f = 0; f < CIN; f++) {
      float4 xv = *reinterpret_cast<const float4*>(&xt[f * RS + s4]);
      float4 wv = *reinterpret_cast<const float4*>(&wL[f * COUT + o0]);
      a0.x += wv.x * xv.x; a0.y += wv.x * xv.y; a0.z += wv.x * xv.z; a0.w += wv.x * xv.w;
      a1.x += wv.y * xv.x; a1.y += wv.y * xv.y; a1.z += wv.y * xv.z; a1.w += wv.y * xv.w;
      a2.x += wv.z * xv.x; a2.y += wv.z * xv.y; a2.z += wv.z * xv.z; a2.w += wv.z * xv.w;
      a3.x += wv.w * xv.x; a3.y += wv.w * xv.y; a3.z += wv.w * xv.z; a3.w += wv.w * xv.w;
    }
    *reinterpret_cast<ushort4*>(&y[((size_t)bl * COUT + o0 + 0) * S + s0 + s4]) = pack4(a0);
    *reinterpret_cast<ushort4*>(&y[((size_t)bl * COUT + o0 + 1) * S + s0 + s4]) = pack4(a1);
    *reinterpret_cast<ushort4*>(&y[((size_t)bl * COUT + o0 + 2) * S + s0 + s4]) = pack4(a2);
    *reinterpret_cast<ushort4*>(&y[((size_t)bl * COUT + o0 + 3) * S + s0 + s4]) = pack4(a3);
  }
}

// ---------------- stats partials over bf16 src ------------------------------
__global__ __launch_bounds__(256) void k_statsPb(const unsigned short* __restrict__ src,
                                                 float* __restrict__ part, int S) {
  int c = blockIdx.x, p = blockIdx.y, bl = blockIdx.z;
  int C = gridDim.x;
  int chunkS = S / NP;
  int s0 = p * chunkS;
  const unsigned short* q = src + ((size_t)bl * C + c) * S;
  float s = 0.f, s2 = 0.f;
  for (int i = s0 + threadIdx.x * 4; i < s0 + chunkS; i += 1024) {
    ushort4 u = *reinterpret_cast<const ushort4*>(&q[i]);
    float a = bf2f(u.x), b = bf2f(u.y), cc = bf2f(u.z), d = bf2f(u.w);
    s += a + b + cc + d;
    s2 += a * a + b * b + cc * cc + d * d;
  }
  for (int off = 32; off; off >>= 1) {
    s += __shfl_down(s, off);
    s2 += __shfl_down(s2, off);
  }
  __shared__ float ls[4], ls2[4];
  int w = threadIdx.x >> 6;
  if ((threadIdx.x & 63) == 0) {
    ls[w] = s;
    ls2[w] = s2;
  }
  __syncthreads();
  if (threadIdx.x == 0) {
    size_t o = (((size_t)bl * C + c) * NP + p) * 2;
    part[o + 0] = ls[0] + ls[1] + ls[2] + ls[3];
    part[o + 1] = ls2[0] + ls2[1] + ls2[2] + ls2[3];
  }
}

// ---------------- stats partials over fp32 src ------------------------------
__global__ __launch_bounds__(256) void k_statsPf(const float* __restrict__ src,
                                                 float* __restrict__ part, int S) {
  int c = blockIdx.x, p = blockIdx.y, bl = blockIdx.z;
  int C = gridDim.x;
  int chunkS = S / NP;
  int s0 = p * chunkS;
  const float* q = src + ((size_t)bl * C + c) * S;
  float s = 0.f, s2 = 0.f;
  for (int i = s0 + threadIdx.x * 4; i < s0 + chunkS; i += 1024) {
    float4 v = *reinterpret_cast<const float4*>(&q[i]);
    s += v.x + v.y + v.z + v.w;
    s2 += v.x * v.x + v.y * v.y + v.z * v.z + v.w * v.w;
  }
  for (int off = 32; off; off >>= 1) {
    s += __shfl_down(s, off);
    s2 += __shfl_down(s2, off);
  }
  __shared__ float ls[4], ls2[4];
  int w = threadIdx.x >> 6;
  if ((threadIdx.x & 63) == 0) {
    ls[w] = s;
    ls2[w] = s2;
  }
  __syncthreads();
  if (threadIdx.x == 0) {
    size_t o = (((size_t)bl * C + c) * NP + p) * 2;
    part[o + 0] = ls[0] + ls[1] + ls[2] + ls[3];
    part[o + 1] = ls2[0] + ls2[1] + ls2[2] + ls2[3];
  }
}

// finalize partials -> (mean, rsigma) into stL[2*C]
template <int C, int S>
__device__ __forceinline__ void finalize_stats(const float* __restrict__ part, int bl,
                                               float* __restrict__ stL, int tid) {
  for (int c = tid; c < C; c += 256) {
    float s = 0.f, s2 = 0.f;
#pragma unroll
    for (int p = 0; p < NP; p++) {
      size_t o = (((size_t)bl * C + c) * NP + p) * 2;
      s += part[o];
      s2 += part[o + 1];
    }
    float m = s / (float)S;
    float v = s2 / (float)S - m * m;
    stL[2 * c] = m;
    stL[2 * c + 1] = rsqrtf(fmaxf(v, 0.f) + 1e-5f);
  }
}

// ---------------- temporal conv as bf16 MFMA GEMM ---------------------------
// c[o,n,t'] = sum_{ci,k} wk[k][o][ci] * relu(IN(y))[ci, n, STRIDE*t'+k-4]
// y is bf16. Weight tiles double-buffered via register prefetch.
template <int C, int TIN, int STRIDE, int BN>
__global__ __launch_bounds__(256) void k_convmma(const unsigned short* __restrict__ y,
                                                 const unsigned short* __restrict__ wkb,
                                                 const float* __restrict__ part,
                                                 float* __restrict__ cbuf) {
  constexpr int TOUT = TIN / STRIDE;
  constexpr int SPAN = STRIDE * BN + 8;   // input t-span incl. halo (mult of 8)
  constexpr int CP = C + 8;               // padded row (bf16 elems)
  constexpr int WM = (C >= 64) ? 2 : 1;
  constexpr int WN = 4 / WM;
  constexpr int MF = C / (16 * WM);
  constexpr int NF = BN / (16 * WN);
  constexpr int WREGS = C * C / 1024;     // ushort4 per thread for one tap

  __shared__ unsigned short zt[SPAN * CP];  // transposed normalized input [t][ci]
  __shared__ unsigned short wl[C * CP];     // current tap weights [o][ci]
  __shared__ float stL[2 * C];

  int t0 = blockIdx.x * BN;
  int n = blockIdx.y;
  int bl = blockIdx.z;
  int tid = threadIdx.x;
  int tin0 = STRIDE * t0 - 4;

  ushort4 wreg[WREGS];
  // issue tap-0 weight loads early
#pragma unroll
  for (int j = 0; j < WREGS; j++)
    wreg[j] = *reinterpret_cast<const ushort4*>(&wkb[(size_t)(tid + j * 256) * 4]);

  finalize_stats<C, NN * TIN>(part, bl, stL, tid);
  __syncthreads();  // stL ready

  // stage normalized+relu input, transposed, bf16 (vectorized global reads)
  const unsigned short* yb = y + ((size_t)bl * C) * NN * TIN + (size_t)n * TIN;
  for (int i = tid * 4; i < C * SPAN; i += 1024) {
    int ci = i / SPAN, r = i - ci * SPAN;
    int t = tin0 + r;
    const unsigned short* yrow = yb + (size_t)ci * NN * TIN;
    float m = stL[2 * ci], rs = stL[2 * ci + 1];
    float zv[4];
    if (t >= 0 && t + 4 <= TIN) {
      ushort4 u = *reinterpret_cast<const ushort4*>(&yrow[t]);
      zv[0] = fmaxf((bf2f(u.x) - m) * rs, 0.f);
      zv[1] = fmaxf((bf2f(u.y) - m) * rs, 0.f);
      zv[2] = fmaxf((bf2f(u.z) - m) * rs, 0.f);
      zv[3] = fmaxf((bf2f(u.w) - m) * rs, 0.f);
    } else {
#pragma unroll
      for (int j = 0; j < 4; j++) {
        int tj = t + j;
        zv[j] = (tj >= 0 && tj < TIN) ? fmaxf((bf2f(yrow[tj]) - m) * rs, 0.f) : 0.f;
      }
    }
#pragma unroll
    for (int j = 0; j < 4; j++) zt[(r + j) * CP + ci] = f2bf(zv[j]);
  }

  // commit tap-0 weights to LDS
#pragma unroll
  for (int j = 0; j < WREGS; j++) {
    int i = (tid + j * 256) * 4;
    int o = i / C, ci = i - o * C;
    *reinterpret_cast<ushort4*>(&wl[o * CP + ci]) = wreg[j];
  }

  int w = tid >> 6;
  int lane = tid & 63;
  int lm = lane & 15, kh = lane >> 4;
  int o0w = (w / WN) * (C / WM);
  int col0 = (w % WN) * (BN / WN);

  f32x4 acc[MF][NF];
#pragma unroll
  for (int mf = 0; mf < MF; mf++)
#pragma unroll
    for (int nf = 0; nf < NF; nf++) acc[mf][nf] = (f32x4){0.f, 0.f, 0.f, 0.f};

  for (int k = 0; k < KK; k++) {
    if (k + 1 < KK) {  // prefetch next tap into regs (hidden under MFMA)
      const unsigned short* wg = wkb + (size_t)(k + 1) * C * C;
#pragma unroll
      for (int j = 0; j < WREGS; j++)
        wreg[j] = *reinterpret_cast<const ushort4*>(&wg[(size_t)(tid + j * 256) * 4]);
    }
    __syncthreads();  // zt + wl[k] ready
#pragma unroll
    for (int ci0 = 0; ci0 < C; ci0 += 32) {
      s16x8 a[MF], b[NF];
#pragma unroll
      for (int mf = 0; mf < MF; mf++)
        a[mf] = *reinterpret_cast<const s16x8*>(&wl[(o0w + mf * 16 + lm) * CP + ci0 + kh * 8]);
#pragma unroll
      for (int nf = 0; nf < NF; nf++) {
        int col = col0 + nf * 16 + lm;
        int r = STRIDE * col + k;
        b[nf] = *reinterpret_cast<const s16x8*>(&zt[r * CP + ci0 + kh * 8]);
      }
#pragma unroll
      for (int mf = 0; mf < MF; mf++)
#pragma unroll
        for (int nf = 0; nf < NF; nf++)
          acc[mf][nf] = __builtin_amdgcn_mfma_f32_16x16x32_bf16(a[mf], b[nf], acc[mf][nf], 0, 0, 0);
    }
    __syncthreads();  // all waves done reading wl[k]
    if (k + 1 < KK) {
#pragma unroll
      for (int j = 0; j < WREGS; j++) {
        int i = (tid + j * 256) * 4;
        int o = i / C, ci = i - o * C;
        *reinterpret_cast<ushort4*>(&wl[o * CP + ci]) = wreg[j];
      }
    }
  }

  // epilogue: D[row=(l>>4)*4+r][col=l&15]
#pragma unroll
  for (int mf = 0; mf < MF; mf++)
#pragma unroll
    for (int nf = 0; nf < NF; nf++) {
      int tp = t0 + col0 + nf * 16 + lm;
#pragma unroll
      for (int rr = 0; rr < 4; rr++) {
        int o = o0w + mf * 16 + kh * 4 + rr;
        cbuf[(((size_t)bl * C + o) * NN + n) * TOUT + tp] = acc[mf][nf][rr];
      }
    }
}

// ------- epilogue: out = relu( relu((c-m2)*rs2) + res(in) + br ) ------------
template <int CIN, int COUT, int TOUT, int STRIDE, bool LAYX>
__global__ __launch_bounds__(256) void k_post(const float* __restrict__ cbuf,
                                              const float* __restrict__ part,
                                              const float* __restrict__ in,
                                              const float* __restrict__ wrt,
                                              const float* __restrict__ br,
                                              float* __restrict__ out, int b0) {
  constexpr int TT = 64;
  constexpr int TIN_ = TOUT * STRIDE;
  __shared__ float inT[CIN * TT];
  __shared__ float wL[CIN * COUT];
  __shared__ float brL[COUT];
  __shared__ float stL[2 * COUT];
  int t0 = blockIdx.x * TT, n = blockIdx.y, bl = blockIdx.z;
  int tid = threadIdx.x;
  for (int i = tid; i < CIN * COUT; i += 256) wL[i] = wrt[i];
  if (tid < COUT) brL[tid] = br[tid];
  finalize_stats<COUT, NN * TOUT>(part, bl, stL, tid);
  for (int i = tid; i < CIN * TT; i += 256) {
    int ci = i / TT, tl = i - ci * TT;
    int t = STRIDE * (t0 + tl);
    float v;
    if (LAYX)
      v = in[(((size_t)(b0 + bl) * NN + n) * TIN_ + t) * CIN + ci];
    else
      v = in[(((size_t)bl * CIN + ci) * NN + n) * TIN_ + t];
    inT[i] = v;
  }
  __syncthreads();
  int tl = tid & 63;
  int o4 = tid >> 6;
  int t = t0 + tl;
  for (int op = 0; op < COUT / 16; op++) {
    int o0 = op * 16 + o4 * 4;
    float accA[4] = {0.f, 0.f, 0.f, 0.f};
    for (int ci = 0; ci < CIN; ci++) {
      float xv = inT[ci * TT + tl];
      float4 wv = *reinterpret_cast<const float4*>(&wL[ci * COUT + o0]);
      accA[0] += wv.x * xv;
      accA[1] += wv.y * xv;
      accA[2] += wv.z * xv;
      accA[3] += wv.w * xv;
    }
#pragma unroll
    for (int q = 0; q < 4; q++) {
      int o = o0 + q;
      float m = stL[2 * o], rs = stL[2 * o + 1];
      float cv = cbuf[(((size_t)bl * COUT + o) * NN + n) * TOUT + t];
      float v = fmaxf((cv - m) * rs, 0.f) + accA[q] + brL[o];
      out[(((size_t)bl * COUT + o) * NN + n) * TOUT + t] = fmaxf(v, 0.f);
    }
  }
}

// ---------------- node-mean pool: pooled[b0+b,t,c] = mean_n src[b,c,n,t] ----
__global__ __launch_bounds__(256) void k_pool(const float* __restrict__ src,
                                              float* __restrict__ pooled, int b0) {
  constexpr int CP = 128, TPZ = 512;
  int t = blockIdx.x * 64 + (threadIdx.x & 63);
  int c = blockIdx.y * 4 + (threadIdx.x >> 6);
  int bl = blockIdx.z;
  const float* p = src + ((size_t)bl * CP + c) * NN * TPZ + t;
  float s = 0.f;
  for (int n = 0; n < NN; n++) s += p[(size_t)n * TPZ];
  pooled[((size_t)(b0 + bl) * TPZ + t) * CP + c] = s * (1.f / NN);
}

// ---------------- attention scores (full batch) -----------------------------
__global__ __launch_bounds__(128) void k_attn1(const float* __restrict__ pooled,
                                               const float* __restrict__ w1,
                                               const float* __restrict__ b1,
                                               const float* __restrict__ w2,
                                               const float* __restrict__ b2v,
                                               float* __restrict__ score) {
  __shared__ float w1L[128 * 64];
  __shared__ float w2L[64];
  __shared__ float b1L[64];
  int b = blockIdx.y;
  int t = blockIdx.x * 128 + threadIdx.x;
  int tid = threadIdx.x;
  for (int i = tid; i < 128 * 64; i += 128) w1L[i] = w1[i];
  if (tid < 64) {
    w2L[tid] = w2[tid];
    b1L[tid] = b1[tid];
  }
  __syncthreads();
  float hid[64];
#pragma unroll
  for (int j = 0; j < 64; j++) hid[j] = b1L[j];
  const float* pv = &pooled[((size_t)b * 512 + t) * 128];
  for (int c = 0; c < 128; c++) {
    float xv = pv[c];
#pragma unroll
    for (int j = 0; j < 64; j++) hid[j] += xv * w1L[c * 64 + j];
  }
  float s = b2v[0];
#pragma unroll
  for (int j = 0; j < 64; j++) s += tanhf(hid[j]) * w2L[j];
  score[(size_t)b * 512 + t] = s;
}

// ---------------- softmax over T'=512 per sample ----------------------------
__global__ __launch_bounds__(256) void k_attn2(const float* __restrict__ score,
                                               float* __restrict__ wgt) {
  __shared__ float sc[512];
  __shared__ float red[4];
  int b = blockIdx.x;
  int tid = threadIdx.x;
  for (int t = tid; t < 512; t += 256) sc[t] = score[(size_t)b * 512 + t];
  __syncthreads();
  float mx = -1e30f;
  for (int t = tid; t < 512; t += 256) mx = fmaxf(mx, sc[t]);
  for (int off = 32; off; off >>= 1) mx = fmaxf(mx, __shfl_down(mx, off));
  if ((tid & 63) == 0) red[tid >> 6] = mx;
  __syncthreads();
  mx = fmaxf(fmaxf(red[0], red[1]), fmaxf(red[2], red[3]));
  __syncthreads();
  float sum = 0.f;
  for (int t = tid; t < 512; t += 256) {
    float e = expf(sc[t] - mx);
    sc[t] = e;
    sum += e;
  }
  for (int off = 32; off; off >>= 1) sum += __shfl_down(sum, off);
  if ((tid & 63) == 0) red[tid >> 6] = sum;
  __syncthreads();
  float inv = 1.f / (red[0] + red[1] + red[2] + red[3]);
  for (int t = tid; t < 512; t += 256) wgt[(size_t)b * 512 + t] = sc[t] * inv;
}

// ---------------- weighted feature chunks -----------------------------------
__global__ __launch_bounds__(256) void k_feat2(const float* __restrict__ pooled,
                                               const float* __restrict__ wgt,
                                               float* __restrict__ featb) {
  __shared__ float sh[16][17];
  int b = blockIdx.y;
  int c0 = blockIdx.x * 16;
  int cl = threadIdx.x & 15, tlane = threadIdx.x >> 4;
  float s = 0.f;
  for (int t = tlane; t < 512; t += 16)
    s += pooled[((size_t)b * 512 + t) * 128 + c0 + cl] * wgt[(size_t)b * 512 + t];
  sh[tlane][cl] = s;
  __syncthreads();
  if (threadIdx.x < 16) {
    float a = 0.f;
    for (int q = 0; q < 16; q++) a += sh[q][threadIdx.x];
    featb[(size_t)b * 128 + c0 + threadIdx.x] = a;
  }
}

// ---------------- logits ----------------------------------------------------
__global__ __launch_bounds__(128) void k_logits(const float* __restrict__ featb,
                                                const float* __restrict__ fcw,
                                                const float* __restrict__ fcb,
                                                float* __restrict__ out) {
  __shared__ float fL[128];
  int b = blockIdx.x;
  fL[threadIdx.x] = featb[(size_t)b * 128 + threadIdx.x];
  __syncthreads();
  if (threadIdx.x < 3) {
    float l = fcb[threadIdx.x];
    for (int cc = 0; cc < 128; cc++) l += fL[cc] * fcw[cc * 3 + threadIdx.x];
    out[(size_t)b * 3 + threadIdx.x] = l;
  }
}

// ============================================================================
extern "C" void kernel_launch(void* const* d_in, const int* in_sizes, int n_in,
                              void* d_out, int out_size, void* d_ws, size_t ws_size,
                              hipStream_t stream) {
  (void)in_sizes; (void)n_in; (void)out_size;
  const float* x = (const float*)d_in[0];
  const float* adj = (const float*)d_in[1];
  const float* gw0 = (const float*)d_in[2];
  const float* cw0 = (const float*)d_in[4];
  const float* rw0 = (const float*)d_in[6];
  const float* rb0 = (const float*)d_in[7];
  const float* gw1 = (const float*)d_in[8];
  const float* cw1 = (const float*)d_in[10];
  const float* rw1 = (const float*)d_in[12];
  const float* rb1 = (const float*)d_in[13];
  const float* gw2 = (const float*)d_in[14];
  const float* cw2 = (const float*)d_in[16];
  const float* rw2 = (const float*)d_in[18];
  const float* rb2 = (const float*)d_in[19];
  const float* aw1 = (const float*)d_in[20];
  const float* ab1 = (const float*)d_in[21];
  const float* aw2 = (const float*)d_in[22];
  const float* ab2 = (const float*)d_in[23];
  const float* fcw = (const float*)d_in[24];
  const float* fcb = (const float*)d_in[25];
  float* out = (float*)d_out;
  float* ws = (float*)d_ws;

  // ---- shared ws region (sizes in floats) ----
  float* a_norm = ws;                                      // 3844
  unsigned short* wk0 = (unsigned short*)(a_norm + 3844);  // 4608 f
  unsigned short* wk1 = (unsigned short*)(a_norm + 3844 + 4608);           // 18432 f
  unsigned short* wk2 = (unsigned short*)(a_norm + 3844 + 4608 + 18432);   // 73728 f
  float* wrt0 = a_norm + 3844 + 4608 + 18432 + 73728;      // 160
  float* wrt1 = wrt0 + 160;                                // 2048
  float* wrt2 = wrt1 + 2048;                               // 8192
  float* pooled = wrt2 + 8192;                             // 2097152
  float* scoreb = pooled + 2097152;                        // 16384
  float* wgtA = scoreb + 16384;                            // 16384
  float* featb = wgtA + 16384;                             // 4096
  float* chunk_base = featb + 4096;
  size_t shared_floats = (size_t)(chunk_base - ws);

  const size_t PS_BUF = 4063232;  // 128*62*512 == 64*62*1024 (floats)
  const size_t per_sample = 3 * PS_BUF + 2 * 1024;

  size_t avail = ws_size / sizeof(float);
  long cap = 1;
  if (avail > shared_floats) cap = (long)((avail - shared_floats) / per_sample);
  int Bc = (int)cap;
  if (Bc < 1) Bc = 1;
  if (Bc > 32) Bc = 32;

  // one-time prep
  k_prep<<<dim3(1), dim3(256), 0, stream>>>(adj, a_norm, out + 96);
  k_wt<<<dim3(64), dim3(256), 0, stream>>>(cw0, wk0, 32, rw0, wrt0, 5);
  k_wt<<<dim3(160), dim3(256), 0, stream>>>(cw1, wk1, 64, rw1, wrt1, 32);
  k_wt<<<dim3(576), dim3(256), 0, stream>>>(cw2, wk2, 128, rw2, wrt2, 64);

  float* sp1 = chunk_base;                      // Bc*1024
  float* sp2 = sp1 + (size_t)Bc * 1024;         // Bc*1024
  float* B1 = sp2 + (size_t)Bc * 1024;
  float* B2 = B1 + (size_t)Bc * PS_BUF;
  float* B3 = B2 + (size_t)Bc * PS_BUF;

  for (int b0 = 0; b0 < 32; b0 += Bc) {
    int bc = (32 - b0 < Bc) ? (32 - b0) : Bc;
    unsigned short* B1u = (unsigned short*)B1;
    unsigned short* B2u = (unsigned short*)B2;
    unsigned short* B3u = (unsigned short*)B3;

    // ---- block 0: 5 -> 32, T 1024, stride 1; in = x (global) ----
    k_spatial0<32><<<dim3(32, 2, bc), dim3(256), 0, stream>>>(x, a_norm, B2u, b0);
    k_wmix<5, 32, 1024><<<dim3(496, bc), dim3(256), 0, stream>>>(B2u, gw0, B3u);
    k_statsPb<<<dim3(32, NP, bc), dim3(256), 0, stream>>>(B3u, sp1, 63488);
    k_convmma<32, 1024, 1, 256><<<dim3(4, NN, bc), dim3(256), 0, stream>>>(B3u, wk0, sp1, B2);
    k_statsPf<<<dim3(32, NP, bc), dim3(256), 0, stream>>>(B2, sp2, 63488);
    k_post<5, 32, 1024, 1, true><<<dim3(16, NN, bc), dim3(256), 0, stream>>>(
        B2, sp2, x, wrt0, rb0, B1, b0);  // A -> B1 (fp32)

    // ---- block 1: 32 -> 64, T 1024->512, stride 2; in = A (B1 fp32) ----
    k_spatial<32, 1024><<<dim3(8, 32, bc), dim3(256), 0, stream>>>(B1, a_norm, B3u);
    k_wmix<32, 64, 1024><<<dim3(992, bc), dim3(256), 0, stream>>>(B3u, gw1, B2u);
    k_statsPb<<<dim3(64, NP, bc), dim3(256), 0, stream>>>(B2u, sp1, 63488);
    k_convmma<64, 1024, 2, 128><<<dim3(4, NN, bc), dim3(256), 0, stream>>>(B2u, wk1, sp1, B3);
    k_statsPf<<<dim3(64, NP, bc), dim3(256), 0, stream>>>(B3, sp2, 31744);
    k_post<32, 64, 512, 2, false><<<dim3(8, NN, bc), dim3(256), 0, stream>>>(
        B3, sp2, B1, wrt1, rb1, B2, b0);  // D -> B2 (fp32)

    // ---- block 2: 64 -> 128, T 512, stride 1; in = D (B2 fp32) ----
    k_spatial<64, 512><<<dim3(4, 64, bc), dim3(256), 0, stream>>>(B2, a_norm, B1u);
    k_wmix<64, 128, 512><<<dim3(496, bc), dim3(256), 0, stream>>>(B1u, gw2, B3u);
    k_statsPb<<<dim3(128, NP, bc), dim3(256), 0, stream>>>(B3u, sp1, 31744);
    k_convmma<128, 512, 1, 128><<<dim3(4, NN, bc), dim3(256), 0, stream>>>(B3u, wk2, sp1, B1);
    k_statsPf<<<dim3(128, NP, bc), dim3(256), 0, stream>>>(B1, sp2, 31744);
    k_post<64, 128, 512, 1, false><<<dim3(8, NN, bc), dim3(256), 0, stream>>>(
        B1, sp2, B2, wrt2, rb2, B3, b0);  // OUT -> B3 (fp32)

    k_pool<<<dim3(8, 32, bc), dim3(256), 0, stream>>>(B3, pooled, b0);
  }

  // ---- head: full batch at once ----
  k_attn1<<<dim3(4, 32), dim3(128), 0, stream>>>(pooled, aw1, ab1, aw2, ab2, scoreb);
  k_attn2<<<dim3(32), dim3(256), 0, stream>>>(scoreb, wgtA);
  k_feat2<<<dim3(8, 32), dim3(256), 0, stream>>>(pooled, wgtA, featb);
  k_logits<<<dim3(32), dim3(128), 0, stream>>>(featb, fcw, fcb, out);
}

// Round 5
// 3084.850 us; speedup vs baseline: 6.4095x; 1.1565x over previous
//
#include <hip/hip_runtime.h>

// ST-GCN classifier forward. Round 5: all inter-kernel activations bf16
// (xs, y, cbuf, A, D, OUT), conv epilogue staged through LDS for coalesced
// bf16 writes, vectorized bf16 staging everywhere. Head stays fp32.

#define NN 62
#define KK 9
#define NP 4  // stats partials

typedef short s16x8 __attribute__((ext_vector_type(8)));
typedef float f32x4 __attribute__((ext_vector_type(4)));

__device__ __forceinline__ unsigned short f2bf(float f) {
  unsigned u = __builtin_bit_cast(unsigned, f);
  u += 0x7FFF + ((u >> 16) & 1);
  return (unsigned short)(u >> 16);
}
__device__ __forceinline__ float bf2f(unsigned short u) {
  unsigned v = ((unsigned)u) << 16;
  return __builtin_bit_cast(float, v);
}
__device__ __forceinline__ ushort4 pack4(float4 a) {
  return (ushort4){f2bf(a.x), f2bf(a.y), f2bf(a.z), f2bf(a.w)};
}

// ---------------- prep: gcn-normalized adjacency + adj passthrough ----------
__global__ __launch_bounds__(256) void k_prep(const float* __restrict__ adj,
                                              float* __restrict__ a_norm,
                                              float* __restrict__ out_adj) {
  __shared__ float dinv[NN];
  int tid = threadIdx.x;
  if (tid < NN) {
    float s = 1.0f;  // self loop
    for (int n = 0; n < NN; n++) s += adj[tid * NN + n];
    dinv[tid] = (s > 0.f) ? rsqrtf(fmaxf(s, 1e-5f)) : 0.f;
  }
  __syncthreads();
  for (int idx = tid; idx < NN * NN; idx += 256) {
    int m = idx / NN, n = idx - m * NN;
    float ah = adj[idx] + ((m == n) ? 1.f : 0.f);
    a_norm[idx] = dinv[m] * ah * dinv[n];
    out_adj[idx] = adj[idx];
  }
}

// ------------- weight prep: conv [o][ci][k] -> bf16 [k][o][ci]; res [o][ci]->[ci][o]
__global__ __launch_bounds__(256) void k_wt(const float* __restrict__ wc,
                                            unsigned short* __restrict__ wkb, int C,
                                            const float* __restrict__ wr,
                                            float* __restrict__ wrt, int CIN) {
  int stride = gridDim.x * blockDim.x;
  int total = C * C * KK;
  for (int i = blockIdx.x * blockDim.x + threadIdx.x; i < total; i += stride) {
    int o = i / (C * KK);
    int r = i - o * C * KK;
    int ci = r / KK;
    int k = r - ci * KK;
    wkb[((size_t)k * C + o) * C + ci] = f2bf(wc[i]);
  }
  int t2 = C * CIN;
  for (int i = blockIdx.x * blockDim.x + threadIdx.x; i < t2; i += stride) {
    int o = i / CIN, ci = i - o * CIN;
    wrt[ci * C + o] = wr[i];
  }
}

// ---------------- block-0 spatial: coalesced (t,f) reads of x ---------------
template <int TT>
__global__ __launch_bounds__(256) void k_spatial0(const float* __restrict__ x,
                                                  const float* __restrict__ a_norm,
                                                  unsigned short* __restrict__ xs, int b0) {
  constexpr int CIN = 5, TIN = 1024;
  constexpr int ROW = TT * CIN;
  __shared__ float xt[NN * ROW];
  __shared__ float aL[NN * NN];
  int t0 = blockIdx.x * TT;
  int mh = blockIdx.y;
  int bl = blockIdx.z;
  int tid = threadIdx.x;
  for (int i = tid; i < NN * NN; i += 256) aL[i] = a_norm[i];
  for (int i = tid; i < NN * ROW; i += 256) {
    int n = i / ROW, r = i - n * ROW;
    xt[i] = x[((size_t)((b0 + bl) * NN + n) * TIN + t0) * CIN + r];
  }
  __syncthreads();
  int m0 = mh * 31;
  for (int task = tid; task < CIN * 31 * TT; task += 256) {
    int f = task / (31 * TT);
    int rem = task - f * (31 * TT);
    int mi = rem / TT;
    int tl = rem - mi * TT;
    int m = m0 + mi;
    float acc = 0.f;
    for (int n = 0; n < NN; n++) acc += aL[m * NN + n] * xt[n * ROW + tl * CIN + f];
    xs[(((size_t)bl * CIN + f) * NN + m) * TIN + t0 + tl] = f2bf(acc);
  }
}

// ---------------- generic spatial mix: bf16 in, bf16 out --------------------
template <int CIN, int TIN>
__global__ __launch_bounds__(256) void k_spatial(const unsigned short* __restrict__ in,
                                                 const float* __restrict__ a_norm,
                                                 unsigned short* __restrict__ xs) {
  constexpr int TT = 128;
  constexpr int RS = TT + 4;
  __shared__ float tile[NN * RS];
  __shared__ float aL[NN * NN];
  int t0 = blockIdx.x * TT;
  int f = blockIdx.y;
  int bl = blockIdx.z;
  int tid = threadIdx.x;
  for (int i = tid; i < NN * NN; i += 256) aL[i] = a_norm[i];
  for (int i = tid * 4; i < NN * TT; i += 1024) {
    int n = i / TT, tl = i - n * TT;
    ushort4 u = *reinterpret_cast<const ushort4*>(&in[(((size_t)bl * CIN + f) * NN + n) * TIN + t0 + tl]);
    tile[n * RS + tl + 0] = bf2f(u.x);
    tile[n * RS + tl + 1] = bf2f(u.y);
    tile[n * RS + tl + 2] = bf2f(u.z);
    tile[n * RS + tl + 3] = bf2f(u.w);
  }
  __syncthreads();
  constexpr int T4 = TT / 4;
  for (int task = tid; task < NN * T4; task += 256) {
    int m = task / T4;
    int t4 = (task - m * T4) * 4;
    float4 acc = {0.f, 0.f, 0.f, 0.f};
    for (int n = 0; n < NN; n++) {
      float av = aL[m * NN + n];
      float4 xv = *reinterpret_cast<const float4*>(&tile[n * RS + t4]);
      acc.x += av * xv.x;
      acc.y += av * xv.y;
      acc.z += av * xv.z;
      acc.w += av * xv.w;
    }
    *reinterpret_cast<ushort4*>(&xs[(((size_t)bl * CIN + f) * NN + m) * TIN + t0 + t4]) = pack4(acc);
  }
}

// ---------------- channel mix: bf16 in, bf16 out ----------------------------
template <int CIN, int COUT, int TIN>
__global__ __launch_bounds__(256) void k_wmix(const unsigned short* __restrict__ xs,
                                              const float* __restrict__ wg,
                                              unsigned short* __restrict__ y) {
  constexpr int S = NN * TIN;
  constexpr int O4L = (COUT / 4 < 16) ? COUT / 4 : 16;
  constexpr int SL = 256 / O4L;
  constexpr int ST = SL * 4;
  constexpr int RS = ST + 4;
  __shared__ float xt[CIN * RS];
  __shared__ float wL[CIN * COUT];
  int s0 = blockIdx.x * ST;
  int bl = blockIdx.y;
  int tid = threadIdx.x;
  for (int i = tid; i < CIN * COUT; i += 256) wL[i] = wg[i];
  for (int i = tid * 4; i < CIN * ST; i += 1024) {
    int f = i / ST, sl = i - f * ST;
    ushort4 u = *reinterpret_cast<const ushort4*>(&xs[((size_t)bl * CIN + f) * S + s0 + sl]);
    xt[f * RS + sl + 0] = bf2f(u.x);
    xt[f * RS + sl + 1] = bf2f(u.y);
    xt[f * RS + sl + 2] = bf2f(u.z);
    xt[f * RS + sl + 3] = bf2f(u.w);
  }
  __syncthreads();
  int s4 = (tid % SL) * 4;
  int o4l = tid / SL;
  constexpr int PASSES = COUT / (4 * O4L);
  for (int op = 0; op < PASSES; op++) {
    int o0 = op * (4 * O4L) + o4l * 4;
    float4 a0 = {0, 0, 0, 0}, a1 = {0, 0, 0, 0}, a2 = {0, 0, 0, 0}, a3 = {0, 0, 0, 0};
    for (int f = 0; f < CIN; f++) {
      float4 xv = *reinterpret_cast<const float4*>(&xt[f * RS + s4]);
      float4 wv = *reinterpret_cast<const float4*>(&wL[f * COUT + o0]);
      a0.x += wv.x * xv.x; a0.y += wv.x * xv.y; a0.z += wv.x * xv.z; a0.w += wv.x * xv.w;
      a1.x += wv.y * xv.x; a1.y += wv.y * xv.y; a1.z += wv.y * xv.z; a1.w += wv.y * xv.w;
      a2.x += wv.z * xv.x; a2.y += wv.z * xv.y; a2.z += wv.z * xv.z; a2.w += wv.z * xv.w;
      a3.x += wv.w * xv.x; a3.y += wv.w * xv.y; a3.z += wv.w * xv.z; a3.w += wv.w * xv.w;
    }
    *reinterpret_cast<ushort4*>(&y[((size_t)bl * COUT + o0 + 0) * S + s0 + s4]) = pack4(a0);
    *reinterpret_cast<ushort4*>(&y[((size_t)bl * COUT + o0 + 1) * S + s0 + s4]) = pack4(a1);
    *reinterpret_cast<ushort4*>(&y[((size_t)bl * COUT + o0 + 2) * S + s0 + s4]) = pack4(a2);
    *reinterpret_cast<ushort4*>(&y[((size_t)bl * COUT + o0 + 3) * S + s0 + s4]) = pack4(a3);
  }
}

// ---------------- stats partials over bf16 src ------------------------------
__global__ __launch_bounds__(256) void k_statsPb(const unsigned short* __restrict__ src,
                                                 float* __restrict__ part, int S) {
  int c = blockIdx.x, p = blockIdx.y, bl = blockIdx.z;
  int C = gridDim.x;
  int chunkS = S / NP;
  int s0 = p * chunkS;
  const unsigned short* q = src + ((size_t)bl * C + c) * S;
  float s = 0.f, s2 = 0.f;
  for (int i = s0 + threadIdx.x * 4; i < s0 + chunkS; i += 1024) {
    ushort4 u = *reinterpret_cast<const ushort4*>(&q[i]);
    float a = bf2f(u.x), b = bf2f(u.y), cc = bf2f(u.z), d = bf2f(u.w);
    s += a + b + cc + d;
    s2 += a * a + b * b + cc * cc + d * d;
  }
  for (int off = 32; off; off >>= 1) {
    s += __shfl_down(s, off);
    s2 += __shfl_down(s2, off);
  }
  __shared__ float ls[4], ls2[4];
  int w = threadIdx.x >> 6;
  if ((threadIdx.x & 63) == 0) {
    ls[w] = s;
    ls2[w] = s2;
  }
  __syncthreads();
  if (threadIdx.x == 0) {
    size_t o = (((size_t)bl * C + c) * NP + p) * 2;
    part[o + 0] = ls[0] + ls[1] + ls[2] + ls[3];
    part[o + 1] = ls2[0] + ls2[1] + ls2[2] + ls2[3];
  }
}

// finalize partials -> (mean, rsigma) into stL[2*C]
template <int C, int S>
__device__ __forceinline__ void finalize_stats(const float* __restrict__ part, int bl,
                                               float* __restrict__ stL, int tid) {
  for (int c = tid; c < C; c += 256) {
    float s = 0.f, s2 = 0.f;
#pragma unroll
    for (int p = 0; p < NP; p++) {
      size_t o = (((size_t)bl * C + c) * NP + p) * 2;
      s += part[o];
      s2 += part[o + 1];
    }
    float m = s / (float)S;
    float v = s2 / (float)S - m * m;
    stL[2 * c] = m;
    stL[2 * c + 1] = rsqrtf(fmaxf(v, 0.f) + 1e-5f);
  }
}

// ---------------- temporal conv as bf16 MFMA GEMM ---------------------------
// cbuf[o,n,t'] = sum_{ci,k} wk[k][o][ci] * relu(IN(y))[ci, n, STRIDE*t'+k-4]
// y bf16 in; cbuf bf16 out via LDS-staged coalesced writes.
template <int C, int TIN, int STRIDE, int BN>
__global__ __launch_bounds__(256) void k_convmma(const unsigned short* __restrict__ y,
                                                 const unsigned short* __restrict__ wkb,
                                                 const float* __restrict__ part,
                                                 unsigned short* __restrict__ cbuf) {
  constexpr int TOUT = TIN / STRIDE;
  constexpr int SPAN = STRIDE * BN + 8;   // input t-span incl. halo (mult of 8)
  constexpr int CP = C + 8;               // padded row (bf16), keeps 16B frag alignment
  constexpr int WM = (C >= 64) ? 2 : 1;
  constexpr int WN = 4 / WM;
  constexpr int MF = C / (16 * WM);
  constexpr int NF = BN / (16 * WN);
  constexpr int WREGS = C * C / 1024;     // ushort4 per thread for one tap
  constexpr int BNP = BN + 8;             // epilogue stage row pitch

  __shared__ unsigned short zt[SPAN * CP];  // transposed normalized input [t][ci]
  __shared__ unsigned short wl[C * CP];     // current tap weights [o][ci]
  __shared__ float stL[2 * C];

  static_assert(C * BNP <= SPAN * CP, "epilogue stage must fit in zt");

  int t0 = blockIdx.x * BN;
  int n = blockIdx.y;
  int bl = blockIdx.z;
  int tid = threadIdx.x;
  int tin0 = STRIDE * t0 - 4;

  ushort4 wreg[WREGS];
#pragma unroll
  for (int j = 0; j < WREGS; j++)
    wreg[j] = *reinterpret_cast<const ushort4*>(&wkb[(size_t)(tid + j * 256) * 4]);

  finalize_stats<C, NN * TIN>(part, bl, stL, tid);
  __syncthreads();  // stL ready

  // stage normalized+relu input, transposed, bf16 (vectorized global reads)
  const unsigned short* yb = y + ((size_t)bl * C) * NN * TIN + (size_t)n * TIN;
  for (int i = tid * 4; i < C * SPAN; i += 1024) {
    int ci = i / SPAN, r = i - ci * SPAN;
    int t = tin0 + r;
    const unsigned short* yrow = yb + (size_t)ci * NN * TIN;
    float m = stL[2 * ci], rs = stL[2 * ci + 1];
    float zv[4];
    if (t >= 0 && t + 4 <= TIN) {
      ushort4 u = *reinterpret_cast<const ushort4*>(&yrow[t]);
      zv[0] = fmaxf((bf2f(u.x) - m) * rs, 0.f);
      zv[1] = fmaxf((bf2f(u.y) - m) * rs, 0.f);
      zv[2] = fmaxf((bf2f(u.z) - m) * rs, 0.f);
      zv[3] = fmaxf((bf2f(u.w) - m) * rs, 0.f);
    } else {
#pragma unroll
      for (int j = 0; j < 4; j++) {
        int tj = t + j;
        zv[j] = (tj >= 0 && tj < TIN) ? fmaxf((bf2f(yrow[tj]) - m) * rs, 0.f) : 0.f;
      }
    }
#pragma unroll
    for (int j = 0; j < 4; j++) zt[(r + j) * CP + ci] = f2bf(zv[j]);
  }

  // commit tap-0 weights to LDS
#pragma unroll
  for (int j = 0; j < WREGS; j++) {
    int i = (tid + j * 256) * 4;
    int o = i / C, ci = i - o * C;
    *reinterpret_cast<ushort4*>(&wl[o * CP + ci]) = wreg[j];
  }

  int w = tid >> 6;
  int lane = tid & 63;
  int lm = lane & 15, kh = lane >> 4;
  int o0w = (w / WN) * (C / WM);
  int col0 = (w % WN) * (BN / WN);

  f32x4 acc[MF][NF];
#pragma unroll
  for (int mf = 0; mf < MF; mf++)
#pragma unroll
    for (int nf = 0; nf < NF; nf++) acc[mf][nf] = (f32x4){0.f, 0.f, 0.f, 0.f};

  for (int k = 0; k < KK; k++) {
    if (k + 1 < KK) {  // prefetch next tap into regs (hidden under MFMA)
      const unsigned short* wg = wkb + (size_t)(k + 1) * C * C;
#pragma unroll
      for (int j = 0; j < WREGS; j++)
        wreg[j] = *reinterpret_cast<const ushort4*>(&wg[(size_t)(tid + j * 256) * 4]);
    }
    __syncthreads();  // zt + wl[k] ready
#pragma unroll
    for (int ci0 = 0; ci0 < C; ci0 += 32) {
      s16x8 a[MF], b[NF];
#pragma unroll
      for (int mf = 0; mf < MF; mf++)
        a[mf] = *reinterpret_cast<const s16x8*>(&wl[(o0w + mf * 16 + lm) * CP + ci0 + kh * 8]);
#pragma unroll
      for (int nf = 0; nf < NF; nf++) {
        int col = col0 + nf * 16 + lm;
        int r = STRIDE * col + k;
        b[nf] = *reinterpret_cast<const s16x8*>(&zt[r * CP + ci0 + kh * 8]);
      }
#pragma unroll
      for (int mf = 0; mf < MF; mf++)
#pragma unroll
        for (int nf = 0; nf < NF; nf++)
          acc[mf][nf] = __builtin_amdgcn_mfma_f32_16x16x32_bf16(a[mf], b[nf], acc[mf][nf], 0, 0, 0);
    }
    __syncthreads();  // all waves done reading wl[k]
    if (k + 1 < KK) {
#pragma unroll
      for (int j = 0; j < WREGS; j++) {
        int i = (tid + j * 256) * 4;
        int o = i / C, ci = i - o * C;
        *reinterpret_cast<ushort4*>(&wl[o * CP + ci]) = wreg[j];
      }
    }
  }

  // epilogue: stage D through LDS (reuse zt), then coalesced bf16 writes.
  // fragment map: D[row=(l>>4)*4+r][col=l&15]
  __syncthreads();  // all MFMA zt reads complete
  unsigned short* ot = zt;
#pragma unroll
  for (int mf = 0; mf < MF; mf++)
#pragma unroll
    for (int nf = 0; nf < NF; nf++) {
      int col = col0 + nf * 16 + lm;
#pragma unroll
      for (int rr = 0; rr < 4; rr++) {
        int o = o0w + mf * 16 + kh * 4 + rr;
        ot[o * BNP + col] = f2bf(acc[mf][nf][rr]);
      }
    }
  __syncthreads();
  for (int i = tid * 4; i < C * BN; i += 1024) {
    int o = i / BN, col = i - o * BN;
    ushort4 v = *reinterpret_cast<const ushort4*>(&ot[o * BNP + col]);
    *reinterpret_cast<ushort4*>(&cbuf[(((size_t)bl * C + o) * NN + n) * TOUT + t0 + col]) = v;
  }
}

// ------- epilogue: out = relu( relu((c-m2)*rs2) + res(in) + br ) ------------
// cbuf bf16, out bf16; residual input: x fp32 (LAYX) else bf16 chunk-local.
template <int CIN, int COUT, int TOUT, int STRIDE, bool LAYX>
__global__ __launch_bounds__(256) void k_post(const unsigned short* __restrict__ cbuf,
                                              const float* __restrict__ part,
                                              const void* __restrict__ in,
                                              const float* __restrict__ wrt,
                                              const float* __restrict__ br,
                                              unsigned short* __restrict__ out, int b0) {
  constexpr int TT = 64;
  constexpr int TIN_ = TOUT * STRIDE;
  __shared__ float inT[CIN * TT];
  __shared__ float wL[CIN * COUT];
  __shared__ float brL[COUT];
  __shared__ float stL[2 * COUT];
  int t0 = blockIdx.x * TT, n = blockIdx.y, bl = blockIdx.z;
  int tid = threadIdx.x;
  for (int i = tid; i < CIN * COUT; i += 256) wL[i] = wrt[i];
  if (tid < COUT) brL[tid] = br[tid];
  finalize_stats<COUT, NN * TOUT>(part, bl, stL, tid);
  for (int i = tid; i < CIN * TT; i += 256) {
    int ci = i / TT, tl = i - ci * TT;
    int t = STRIDE * (t0 + tl);
    float v;
    if (LAYX)
      v = ((const float*)in)[(((size_t)(b0 + bl) * NN + n) * TIN_ + t) * CIN + ci];
    else
      v = bf2f(((const unsigned short*)in)[(((size_t)bl * CIN + ci) * NN + n) * TIN_ + t]);
    inT[i] = v;
  }
  __syncthreads();
  int tl = tid & 63;
  int o4 = tid >> 6;
  int t = t0 + tl;
  for (int op = 0; op < COUT / 16; op++) {
    int o0 = op * 16 + o4 * 4;
    float accA[4] = {0.f, 0.f, 0.f, 0.f};
    for (int ci = 0; ci < CIN; ci++) {
      float xv = inT[ci * TT + tl];
      float4 wv = *reinterpret_cast<const float4*>(&wL[ci * COUT + o0]);
      accA[0] += wv.x * xv;
      accA[1] += wv.y * xv;
      accA[2] += wv.z * xv;
      accA[3] += wv.w * xv;
    }
#pragma unroll
    for (int q = 0; q < 4; q++) {
      int o = o0 + q;
      float m = stL[2 * o], rs = stL[2 * o + 1];
      float cv = bf2f(cbuf[(((size_t)bl * COUT + o) * NN + n) * TOUT + t]);
      float v = fmaxf((cv - m) * rs, 0.f) + accA[q] + brL[o];
      out[(((size_t)bl * COUT + o) * NN + n) * TOUT + t] = f2bf(fmaxf(v, 0.f));
    }
  }
}

// ---------------- node-mean pool: pooled[b0+b,t,c] = mean_n src[b,c,n,t] ----
__global__ __launch_bounds__(256) void k_pool(const unsigned short* __restrict__ src,
                                              float* __restrict__ pooled, int b0) {
  constexpr int CP = 128, TPZ = 512;
  int t = blockIdx.x * 64 + (threadIdx.x & 63);
  int c = blockIdx.y * 4 + (threadIdx.x >> 6);
  int bl = blockIdx.z;
  const unsigned short* p = src + ((size_t)bl * CP + c) * NN * TPZ + t;
  float s = 0.f;
  for (int n = 0; n < NN; n++) s += bf2f(p[(size_t)n * TPZ]);
  pooled[((size_t)(b0 + bl) * TPZ + t) * CP + c] = s * (1.f / NN);
}

// ---------------- attention scores (full batch) -----------------------------
__global__ __launch_bounds__(128) void k_attn1(const float* __restrict__ pooled,
                                               const float* __restrict__ w1,
                                               const float* __restrict__ b1,
                                               const float* __restrict__ w2,
                                               const float* __restrict__ b2v,
                                               float* __restrict__ score) {
  __shared__ float w1L[128 * 64];
  __shared__ float w2L[64];
  __shared__ float b1L[64];
  int b = blockIdx.y;
  int t = blockIdx.x * 128 + threadIdx.x;
  int tid = threadIdx.x;
  for (int i = tid; i < 128 * 64; i += 128) w1L[i] = w1[i];
  if (tid < 64) {
    w2L[tid] = w2[tid];
    b1L[tid] = b1[tid];
  }
  __syncthreads();
  float hid[64];
#pragma unroll
  for (int j = 0; j < 64; j++) hid[j] = b1L[j];
  const float* pv = &pooled[((size_t)b * 512 + t) * 128];
  for (int c = 0; c < 128; c++) {
    float xv = pv[c];
#pragma unroll
    for (int j = 0; j < 64; j++) hid[j] += xv * w1L[c * 64 + j];
  }
  float s = b2v[0];
#pragma unroll
  for (int j = 0; j < 64; j++) s += tanhf(hid[j]) * w2L[j];
  score[(size_t)b * 512 + t] = s;
}

// ---------------- softmax over T'=512 per sample ----------------------------
__global__ __launch_bounds__(256) void k_attn2(const float* __restrict__ score,
                                               float* __restrict__ wgt) {
  __shared__ float sc[512];
  __shared__ float red[4];
  int b = blockIdx.x;
  int tid = threadIdx.x;
  for (int t = tid; t < 512; t += 256) sc[t] = score[(size_t)b * 512 + t];
  __syncthreads();
  float mx = -1e30f;
  for (int t = tid; t < 512; t += 256) mx = fmaxf(mx, sc[t]);
  for (int off = 32; off; off >>= 1) mx = fmaxf(mx, __shfl_down(mx, off));
  if ((tid & 63) == 0) red[tid >> 6] = mx;
  __syncthreads();
  mx = fmaxf(fmaxf(red[0], red[1]), fmaxf(red[2], red[3]));
  __syncthreads();
  float sum = 0.f;
  for (int t = tid; t < 512; t += 256) {
    float e = expf(sc[t] - mx);
    sc[t] = e;
    sum += e;
  }
  for (int off = 32; off; off >>= 1) sum += __shfl_down(sum, off);
  if ((tid & 63) == 0) red[tid >> 6] = sum;
  __syncthreads();
  float inv = 1.f / (red[0] + red[1] + red[2] + red[3]);
  for (int t = tid; t < 512; t += 256) wgt[(size_t)b * 512 + t] = sc[t] * inv;
}

// ---------------- weighted feature chunks -----------------------------------
__global__ __launch_bounds__(256) void k_feat2(const float* __restrict__ pooled,
                                               const float* __restrict__ wgt,
                                               float* __restrict__ featb) {
  __shared__ float sh[16][17];
  int b = blockIdx.y;
  int c0 = blockIdx.x * 16;
  int cl = threadIdx.x & 15, tlane = threadIdx.x >> 4;
  float s = 0.f;
  for (int t = tlane; t < 512; t += 16)
    s += pooled[((size_t)b * 512 + t) * 128 + c0 + cl] * wgt[(size_t)b * 512 + t];
  sh[tlane][cl] = s;
  __syncthreads();
  if (threadIdx.x < 16) {
    float a = 0.f;
    for (int q = 0; q < 16; q++) a += sh[q][threadIdx.x];
    featb[(size_t)b * 128 + c0 + threadIdx.x] = a;
  }
}

// ---------------- logits ----------------------------------------------------
__global__ __launch_bounds__(128) void k_logits(const float* __restrict__ featb,
                                                const float* __restrict__ fcw,
                                                const float* __restrict__ fcb,
                                                float* __restrict__ out) {
  __shared__ float fL[128];
  int b = blockIdx.x;
  fL[threadIdx.x] = featb[(size_t)b * 128 + threadIdx.x];
  __syncthreads();
  if (threadIdx.x < 3) {
    float l = fcb[threadIdx.x];
    for (int cc = 0; cc < 128; cc++) l += fL[cc] * fcw[cc * 3 + threadIdx.x];
    out[(size_t)b * 3 + threadIdx.x] = l;
  }
}

// ============================================================================
extern "C" void kernel_launch(void* const* d_in, const int* in_sizes, int n_in,
                              void* d_out, int out_size, void* d_ws, size_t ws_size,
                              hipStream_t stream) {
  (void)in_sizes; (void)n_in; (void)out_size;
  const float* x = (const float*)d_in[0];
  const float* adj = (const float*)d_in[1];
  const float* gw0 = (const float*)d_in[2];
  const float* cw0 = (const float*)d_in[4];
  const float* rw0 = (const float*)d_in[6];
  const float* rb0 = (const float*)d_in[7];
  const float* gw1 = (const float*)d_in[8];
  const float* cw1 = (const float*)d_in[10];
  const float* rw1 = (const float*)d_in[12];
  const float* rb1 = (const float*)d_in[13];
  const float* gw2 = (const float*)d_in[14];
  const float* cw2 = (const float*)d_in[16];
  const float* rw2 = (const float*)d_in[18];
  const float* rb2 = (const float*)d_in[19];
  const float* aw1 = (const float*)d_in[20];
  const float* ab1 = (const float*)d_in[21];
  const float* aw2 = (const float*)d_in[22];
  const float* ab2 = (const float*)d_in[23];
  const float* fcw = (const float*)d_in[24];
  const float* fcb = (const float*)d_in[25];
  float* out = (float*)d_out;
  float* ws = (float*)d_ws;

  // ---- shared ws region (sizes in floats) ----
  float* a_norm = ws;                                      // 3844
  unsigned short* wk0 = (unsigned short*)(a_norm + 3844);  // 4608 f
  unsigned short* wk1 = (unsigned short*)(a_norm + 3844 + 4608);           // 18432 f
  unsigned short* wk2 = (unsigned short*)(a_norm + 3844 + 4608 + 18432);   // 73728 f
  float* wrt0 = a_norm + 3844 + 4608 + 18432 + 73728;      // 160
  float* wrt1 = wrt0 + 160;                                // 2048
  float* wrt2 = wrt1 + 2048;                               // 8192
  float* pooled = wrt2 + 8192;                             // 2097152
  float* scoreb = pooled + 2097152;                        // 16384
  float* wgtA = scoreb + 16384;                            // 16384
  float* featb = wgtA + 16384;                             // 4096
  float* chunk_base = featb + 4096;
  size_t shared_floats = (size_t)(chunk_base - ws);

  // per-sample buffers now bf16: 4063232 elems = 2031616 float-slots each
  const size_t PS_BUF = 2031616;
  const size_t per_sample = 3 * PS_BUF + 2 * 1024;

  size_t avail = ws_size / sizeof(float);
  long cap = 1;
  if (avail > shared_floats) cap = (long)((avail - shared_floats) / per_sample);
  int Bc = (int)cap;
  if (Bc < 1) Bc = 1;
  if (Bc > 32) Bc = 32;

  // one-time prep
  k_prep<<<dim3(1), dim3(256), 0, stream>>>(adj, a_norm, out + 96);
  k_wt<<<dim3(64), dim3(256), 0, stream>>>(cw0, wk0, 32, rw0, wrt0, 5);
  k_wt<<<dim3(160), dim3(256), 0, stream>>>(cw1, wk1, 64, rw1, wrt1, 32);
  k_wt<<<dim3(576), dim3(256), 0, stream>>>(cw2, wk2, 128, rw2, wrt2, 64);

  float* sp1 = chunk_base;                      // Bc*1024
  float* sp2 = sp1 + (size_t)Bc * 1024;         // Bc*1024
  float* B1 = sp2 + (size_t)Bc * 1024;
  float* B2 = B1 + (size_t)Bc * PS_BUF;
  float* B3 = B2 + (size_t)Bc * PS_BUF;

  for (int b0 = 0; b0 < 32; b0 += Bc) {
    int bc = (32 - b0 < Bc) ? (32 - b0) : Bc;
    unsigned short* B1u = (unsigned short*)B1;
    unsigned short* B2u = (unsigned short*)B2;
    unsigned short* B3u = (unsigned short*)B3;

    // ---- block 0: 5 -> 32, T 1024, stride 1; in = x (global fp32) ----
    k_spatial0<32><<<dim3(32, 2, bc), dim3(256), 0, stream>>>(x, a_norm, B2u, b0);
    k_wmix<5, 32, 1024><<<dim3(496, bc), dim3(256), 0, stream>>>(B2u, gw0, B3u);
    k_statsPb<<<dim3(32, NP, bc), dim3(256), 0, stream>>>(B3u, sp1, 63488);
    k_convmma<32, 1024, 1, 256><<<dim3(4, NN, bc), dim3(256), 0, stream>>>(B3u, wk0, sp1, B2u);
    k_statsPb<<<dim3(32, NP, bc), dim3(256), 0, stream>>>(B2u, sp2, 63488);
    k_post<5, 32, 1024, 1, true><<<dim3(16, NN, bc), dim3(256), 0, stream>>>(
        B2u, sp2, x, wrt0, rb0, B1u, b0);  // A -> B1u

    // ---- block 1: 32 -> 64, T 1024->512, stride 2; in = A (B1u) ----
    k_spatial<32, 1024><<<dim3(8, 32, bc), dim3(256), 0, stream>>>(B1u, a_norm, B3u);
    k_wmix<32, 64, 1024><<<dim3(992, bc), dim3(256), 0, stream>>>(B3u, gw1, B2u);
    k_statsPb<<<dim3(64, NP, bc), dim3(256), 0, stream>>>(B2u, sp1, 63488);
    k_convmma<64, 1024, 2, 128><<<dim3(4, NN, bc), dim3(256), 0, stream>>>(B2u, wk1, sp1, B3u);
    k_statsPb<<<dim3(64, NP, bc), dim3(256), 0, stream>>>(B3u, sp2, 31744);
    k_post<32, 64, 512, 2, false><<<dim3(8, NN, bc), dim3(256), 0, stream>>>(
        B3u, sp2, B1u, wrt1, rb1, B2u, b0);  // D -> B2u

    // ---- block 2: 64 -> 128, T 512, stride 1; in = D (B2u) ----
    k_spatial<64, 512><<<dim3(4, 64, bc), dim3(256), 0, stream>>>(B2u, a_norm, B1u);
    k_wmix<64, 128, 512><<<dim3(496, bc), dim3(256), 0, stream>>>(B1u, gw2, B3u);
    k_statsPb<<<dim3(128, NP, bc), dim3(256), 0, stream>>>(B3u, sp1, 31744);
    k_convmma<128, 512, 1, 128><<<dim3(4, NN, bc), dim3(256), 0, stream>>>(B3u, wk2, sp1, B1u);
    k_statsPb<<<dim3(128, NP, bc), dim3(256), 0, stream>>>(B1u, sp2, 31744);
    k_post<64, 128, 512, 1, false><<<dim3(8, NN, bc), dim3(256), 0, stream>>>(
        B1u, sp2, B2u, wrt2, rb2, B3u, b0);  // OUT -> B3u

    k_pool<<<dim3(8, 32, bc), dim3(256), 0, stream>>>(B3u, pooled, b0);
  }

  // ---- head: full batch at once (fp32) ----
  k_attn1<<<dim3(4, 32), dim3(128), 0, stream>>>(pooled, aw1, ab1, aw2, ab2, scoreb);
  k_attn2<<<dim3(32), dim3(256), 0, stream>>>(scoreb, wgtA);
  k_feat2<<<dim3(8, 32), dim3(256), 0, stream>>>(pooled, wgtA, featb);
  k_logits<<<dim3(32), dim3(128), 0, stream>>>(featb, fcw, fcb, out);
}